// Round 7
// baseline (1095.498 us; speedup 1.0000x reference)
//
#include <hip/hip_runtime.h>
#include <cfloat>
#include <cmath>

#define TPB 256

typedef _Float16 half8 __attribute__((ext_vector_type(8)));
typedef float floatx16 __attribute__((ext_vector_type(16)));

__device__ __forceinline__ float wave_reduce_sum(float v) {
#pragma unroll
  for (int off = 32; off > 0; off >>= 1) v += __shfl_xor(v, off, 64);
  return v;
}

// ---------------------------------------------------------------------------
// Kernel 0: build conv2 B-fragments (2-part f16 split) for both encoders.
// frag value B[k][n] = w2[n][c][tap], c = half*16 + k, k = kg*8+j.
// Storage: [enc][fragidx = ks*4+part*2+nt][lane][16B], lane = kg*32+n32.
// ---------------------------------------------------------------------------
__global__ __launch_bounds__(64) void prep_bfrags(
    const float* __restrict__ ce_w2, const float* __restrict__ ge_w2,
    float* __restrict__ frags) {
  const int blk = blockIdx.x;  // 144 = 2 enc x 72 frags
  const int enc = blk / 72;
  const int frag = blk % 72;
  const int ks = frag >> 2, part = (frag >> 1) & 1, nt = frag & 1;
  const int tap = ks >> 1, half = ks & 1;
  const int lane = threadIdx.x;
  const float* w2 = enc ? ge_w2 : ce_w2;
  const int n = nt * 32 + (lane & 31);
  const int cb = half * 16 + (lane >> 5) * 8;
  half8 out;
#pragma unroll
  for (int j = 0; j < 8; ++j) {
    float v = w2[(n * 32 + cb + j) * 9 + tap];
    _Float16 h = (_Float16)v;
    out[j] = (part == 0) ? h : (_Float16)((v - (float)h) * 4096.f);
  }
  *(half8*)((char*)frags + ((size_t)blk * 64 + lane) * 16) = out;
}

// ---------------------------------------------------------------------------
// Kernel 1: memory row inverse norms
// ---------------------------------------------------------------------------
__global__ __launch_bounds__(256) void norm_kernel(
    const float* __restrict__ memg, float* __restrict__ invn) {
  const int wv = threadIdx.x >> 6, lane = threadIdx.x & 63;
  const int row = blockIdx.x * 4 + wv;
  const float* r = memg + (size_t)row * 128;
  float a = r[lane], b = r[lane + 64];
  float s = wave_reduce_sum(a * a + b * b);
  if (lane == 0) invn[row] = 1.f / fmaxf(sqrtf(s), 1e-12f);
}

// ---------------------------------------------------------------------------
// Kernel 2: MFMA encoder, software-pipelined bands.
// Bands of 7 output rows (9 stored), DOUBLE-BUFFERED: between two barriers,
// conv1(band i+1) and conv2(band i) both execute, with wave-role alternation
// (waves 0,1: conv1 first; waves 2,3: conv2 first) so the VALU work of conv1
// overlaps the MFMA/LDS work of conv2 deterministically.
// Global B-fragments are software-prefetched one tap-group ahead.
// conv2 GEMM via v_mfma_f32_32x32x16_f16: D = Ah*Bh + 2^-12(Ah*Bl' + Al'*Bh).
// ---------------------------------------------------------------------------
template <int S, bool CENTER>
__device__ __forceinline__ void encoder_body(
    char* smem, const float* __restrict__ x, const float* __restrict__ w1,
    const float* __restrict__ b1, const float* __restrict__ b2,
    const float* __restrict__ fcw, const float* __restrict__ fcb,
    const float* __restrict__ bfrag, float* __restrict__ zout, int zoff,
    int b) {
  constexpr int SP = S + 2;               // padded width
  constexpr int NBANDS = S / 7;           // 4 (global) / 2 (center)
  constexpr int NPIX = 9 * SP;            // stored rows = 9 (7 + 2 halo)
  constexpr int GSTB = NPIX * 16;         // ch-group stride bytes
  constexpr int PSTB = 4 * GSTB;          // part stride bytes
  constexpr int BUFB = 2 * PSTB;          // one band buffer (both parts)
  constexpr int LIMIT = 7 * S;            // valid px per band (196 / 98)
  constexpr int MTB = (LIMIT + 31) / 32;  // 7 / 4
  constexpr int NBLK2 = (MTB + 1) / 2;    // 4 / 2 M-blocks per band

  char* h1s = smem;                       // 2 band buffers
  float* xs = (float*)(smem + 2 * BUFB);
  float* w1s = xs + SP * SP;
  float(*featp)[64] = (float(*)[64])(w1s + 288);

  const int t = threadIdx.x;
  const int lane = t & 63;
  const int wv = t >> 6;

  for (int e = t; e < SP * SP; e += TPB) xs[e] = 0.f;
  for (int e = t; e < 288; e += TPB) w1s[e] = w1[e];
  __syncthreads();
  const float* xb = x + (size_t)b * 784 + (CENTER ? (7 * 28 + 7) : 0);
  for (int e = t; e < S * S; e += TPB) {
    int i = e / S, j = e - i * S;
    xs[(i + 1) * SP + (j + 1)] = xb[i * 28 + j];
  }
  __syncthreads();

  float sp0 = 0.f, sp1 = 0.f;
  const float bias0 = b2[lane & 31];
  const float bias1 = b2[32 + (lane & 31)];
  const int gOff = (lane >> 5) * GSTB;
  const char* bgbase = (const char*)bfrag + lane * 16;

  // conv1 for one band: wave wv produces channel-group g = wv.
  auto conv1_band = [&](int i) {
    const int b0 = i * 7;
    char* buf = h1s + (i & 1) * BUFB + wv * GSTB;
    for (int pix = lane; pix < NPIX; pix += 64) {
      int lr = pix / SP;
      int cw = pix - lr * SP;
      int gr = b0 - 1 + lr;
      half8 hi8 = {}, lo8 = {};
      if (gr >= 0 && gr < S && cw >= 1 && cw <= S) {
        float xv[9];
#pragma unroll
        for (int di = 0; di < 3; ++di)
#pragma unroll
          for (int dj = 0; dj < 3; ++dj)
            xv[di * 3 + dj] = xs[(gr + di) * SP + (cw - 1 + dj)];
#pragma unroll
        for (int u = 0; u < 8; ++u) {
          int ch = wv * 8 + u;
          float a = b1[ch];
#pragma unroll
          for (int v = 0; v < 9; ++v) a += xv[v] * w1s[ch * 9 + v];
          a = fmaxf(a, 0.f);
          _Float16 h = (_Float16)a;
          hi8[u] = h;
          lo8[u] = (_Float16)((a - (float)h) * 4096.f);
        }
      }
      *(half8*)(buf + pix * 16) = hi8;
      *(half8*)(buf + PSTB + pix * 16) = lo8;
    }
  };

  // conv2 (one M-block per eligible wave) + pooling for one band.
  auto conv2_band = [&](int i) {
    int mblk;
    if (NBLK2 == 4) {
      mblk = wv;
    } else {
      if (!(wv & 1)) return;  // waves 1,3 own the 2 M-blocks
      mblk = wv >> 1;
    }
    const char* buf = h1s + (i & 1) * BUFB;
    const int Mt0 = mblk * 2;
    floatx16 acc[2][2][2] = {};  // [Mtile][Ntile][term hi/lo]
    int pixB[2];
#pragma unroll
    for (int im = 0; im < 2; ++im) {
      int px = (Mt0 + im) * 32 + (lane & 31);
      px = px < LIMIT ? px : LIMIT - 1;
      int o = px / S;
      int c = px - o * S;
      pixB[im] = (o * SP + c) * 16;
    }
    // prefetch group 0 B-fragments
    half8 nb0 = *(const half8*)(bgbase);
    half8 nb1 = *(const half8*)(bgbase + 1024);
    half8 nb2 = *(const half8*)(bgbase + 2048);
    half8 nb3 = *(const half8*)(bgbase + 3072);
#pragma unroll
    for (int ks = 0; ks < 18; ++ks) {
      half8 bh0 = nb0, bh1 = nb1, bl0 = nb2, bl1 = nb3;
      if (ks < 17) {
        const char* np = bgbase + (ks + 1) * 4096;
        nb0 = *(const half8*)(np);
        nb1 = *(const half8*)(np + 1024);
        nb2 = *(const half8*)(np + 2048);
        nb3 = *(const half8*)(np + 3072);
      }
      const int tap = ks >> 1, half = ks & 1;
      const int offA =
          ((tap / 3) * SP + (tap % 3)) * 16 + gOff + half * (2 * GSTB);
      half8 ah0 = *(const half8*)(buf + pixB[0] + offA);
      half8 al0 = *(const half8*)(buf + PSTB + pixB[0] + offA);
      half8 ah1 = *(const half8*)(buf + pixB[1] + offA);
      half8 al1 = *(const half8*)(buf + PSTB + pixB[1] + offA);
      acc[0][0][0] =
          __builtin_amdgcn_mfma_f32_32x32x16_f16(ah0, bh0, acc[0][0][0], 0, 0, 0);
      acc[0][0][1] =
          __builtin_amdgcn_mfma_f32_32x32x16_f16(ah0, bl0, acc[0][0][1], 0, 0, 0);
      acc[0][0][1] =
          __builtin_amdgcn_mfma_f32_32x32x16_f16(al0, bh0, acc[0][0][1], 0, 0, 0);
      acc[1][0][0] =
          __builtin_amdgcn_mfma_f32_32x32x16_f16(ah1, bh0, acc[1][0][0], 0, 0, 0);
      acc[1][0][1] =
          __builtin_amdgcn_mfma_f32_32x32x16_f16(ah1, bl0, acc[1][0][1], 0, 0, 0);
      acc[1][0][1] =
          __builtin_amdgcn_mfma_f32_32x32x16_f16(al1, bh0, acc[1][0][1], 0, 0, 0);
      acc[0][1][0] =
          __builtin_amdgcn_mfma_f32_32x32x16_f16(ah0, bh1, acc[0][1][0], 0, 0, 0);
      acc[0][1][1] =
          __builtin_amdgcn_mfma_f32_32x32x16_f16(ah0, bl1, acc[0][1][1], 0, 0, 0);
      acc[0][1][1] =
          __builtin_amdgcn_mfma_f32_32x32x16_f16(al0, bh1, acc[0][1][1], 0, 0, 0);
      acc[1][1][0] =
          __builtin_amdgcn_mfma_f32_32x32x16_f16(ah1, bh1, acc[1][1][0], 0, 0, 0);
      acc[1][1][1] =
          __builtin_amdgcn_mfma_f32_32x32x16_f16(ah1, bl1, acc[1][1][1], 0, 0, 0);
      acc[1][1][1] =
          __builtin_amdgcn_mfma_f32_32x32x16_f16(al1, bh1, acc[1][1][1], 0, 0, 0);
    }
    // pool: feat[n] += relu(D + bias), D = acc_hi + acc_lo * 2^-12
#pragma unroll
    for (int im = 0; im < 2; ++im)
#pragma unroll
      for (int reg = 0; reg < 16; ++reg) {
        int row = (reg & 3) + 8 * (reg >> 2) + 4 * (lane >> 5);
        int p = (Mt0 + im) * 32 + row;
        if (p < LIMIT) {
          float v0 =
              acc[im][0][0][reg] + acc[im][0][1][reg] * (1.f / 4096.f) + bias0;
          float v1 =
              acc[im][1][0][reg] + acc[im][1][1][reg] * (1.f / 4096.f) + bias1;
          sp0 += fmaxf(v0, 0.f);
          sp1 += fmaxf(v1, 0.f);
        }
      }
  };

  conv1_band(0);
  __syncthreads();
#pragma unroll
  for (int i = 0; i < NBANDS; ++i) {
    if (wv < 2) {  // role A: produce next band, then consume current
      if (i + 1 < NBANDS) conv1_band(i + 1);
      conv2_band(i);
    } else {       // role B: consume current, then produce next band
      conv2_band(i);
      if (i + 1 < NBANDS) conv1_band(i + 1);
    }
    __syncthreads();
  }

  sp0 += __shfl_xor(sp0, 32);
  sp1 += __shfl_xor(sp1, 32);
  if (lane < 32) {
    featp[wv][lane] = sp0;
    featp[wv][32 + lane] = sp1;
  }
  __syncthreads();
  if (t < 64)
    featp[0][t] = (featp[0][t] + featp[1][t] + featp[2][t] + featp[3][t]) *
                  (1.f / (S * S));
  __syncthreads();
  if (t < 64) {
    float s = 0.f;
#pragma unroll
    for (int i = 0; i < 64; ++i) s += featp[0][i] * fcw[t * 64 + i];
    zout[(size_t)b * 128 + zoff + t] = s + fcb[t];
  }
}

// Fused launch: blocks 0..2047 = global encoder, 2048..4095 = center encoder.
// LDS: 2*BUFB(S=28)=69120 + xs 3600 + w1s 1152 + featp 1024 = 74896 B
// -> 2 blocks/CU.
__global__ __launch_bounds__(256, 2) void encoders_fused(
    const float* __restrict__ x, const float* __restrict__ ce_w1,
    const float* __restrict__ ce_b1, const float* __restrict__ ce_b2,
    const float* __restrict__ ce_fcw, const float* __restrict__ ce_fcb,
    const float* __restrict__ ge_w1, const float* __restrict__ ge_b1,
    const float* __restrict__ ge_b2, const float* __restrict__ ge_fcw,
    const float* __restrict__ ge_fcb, const float* __restrict__ frags,
    float* __restrict__ z) {
  __shared__ __align__(16) char smem[74896];
  if (blockIdx.x < 2048)
    encoder_body<28, false>(smem, x, ge_w1, ge_b1, ge_b2, ge_fcw, ge_fcb,
                            frags + 18432, z, 64, blockIdx.x);
  else
    encoder_body<14, true>(smem, x, ce_w1, ce_b1, ce_b2, ce_fcw, ce_fcb, frags,
                           z, 0, blockIdx.x - 2048);
}

// ---------------------------------------------------------------------------
// Kernel 3a: partial match. Grid (256 z-groups, 4 mem-quarters).
// ---------------------------------------------------------------------------
__global__ __launch_bounds__(256) void match_part(
    const float* __restrict__ z, const float* __restrict__ memg,
    const float* __restrict__ invn, float* __restrict__ topvw,
    int* __restrict__ topiw) {
  __shared__ __align__(16) float zs[8][128];
  __shared__ float qv[8][512];
  __shared__ int qi[8][512];
  __shared__ int qn[8];
  __shared__ float rowmin[8];

  const int t = threadIdx.x;
  const int rowbase = blockIdx.x * 8;
  const int mbase = blockIdx.y * 2048;

  for (int e = t; e < 8 * 128; e += TPB) {
    int r = e >> 7, j = e & 127;
    zs[r][j] = z[(size_t)(rowbase + r) * 128 + j];
  }
  if (t < 8) { qn[t] = 0; rowmin[t] = -FLT_MAX; }
  __syncthreads();
  {
    int wv = t >> 6, lane = t & 63;
#pragma unroll
    for (int h = 0; h < 2; ++h) {
      int r = wv + h * 4;
      float a = zs[r][lane], b = zs[r][lane + 64];
      float s = wave_reduce_sum(a * a + b * b);
      float inv = 1.f / fmaxf(sqrtf(s), 1e-12f);
      zs[r][lane] = a * inv;
      zs[r][lane + 64] = b * inv;
    }
  }
  __syncthreads();

  float av[10];
  int ai[10];
#pragma unroll
  for (int i = 0; i < 10; ++i) { av[i] = -FLT_MAX; ai[i] = 0; }

  for (int mt = 0; mt < 4; ++mt) {
    int m0 = mbase + mt * 512 + t;
    float acc0[8] = {}, acc1[8] = {};
    const float4* mr0 = (const float4*)(memg + (size_t)m0 * 128);
    const float4* mr1 = (const float4*)(memg + (size_t)(m0 + 256) * 128);
#pragma unroll 4
    for (int jq = 0; jq < 32; ++jq) {
      float4 a0 = mr0[jq], a1 = mr1[jq];
#pragma unroll
      for (int r = 0; r < 8; ++r) {
        float4 zv = ((const float4*)zs[r])[jq];
        acc0[r] += a0.x * zv.x + a0.y * zv.y + a0.z * zv.z + a0.w * zv.w;
        acc1[r] += a1.x * zv.x + a1.y * zv.y + a1.z * zv.z + a1.w * zv.w;
      }
    }
    float i0 = invn[m0], i1 = invn[m0 + 256];
#pragma unroll
    for (int r = 0; r < 8; ++r) {
      float rm = rowmin[r];
      float v0 = acc0[r] * i0;
      if (v0 > rm) {
        int k = atomicAdd(&qn[r], 1);
        qv[r][k] = v0; qi[r][k] = m0;
      }
      float v1 = acc1[r] * i1;
      if (v1 > rm) {
        int k = atomicAdd(&qn[r], 1);
        qv[r][k] = v1; qi[r][k] = m0 + 256;
      }
    }
    __syncthreads();
    if (t < 8) {
      int n = qn[t];
      for (int k = 0; k < n; ++k) {
        float v = qv[t][k];
        int m = qi[t][k];
        if (v > av[9]) {
#pragma unroll
          for (int i = 0; i < 10; ++i) {
            if (v > av[i]) {
              float tv = av[i]; av[i] = v; v = tv;
              int ti = ai[i]; ai[i] = m; m = ti;
            }
          }
        }
      }
      qn[t] = 0;
      rowmin[t] = av[9];
    }
    __syncthreads();
  }

  if (t < 8) {
    const size_t base = (size_t)(rowbase + t) * 40 + blockIdx.y * 10;
#pragma unroll
    for (int k = 0; k < 10; ++k) {
      topvw[base + k] = av[k];
      topiw[base + k] = ai[k];
    }
  }
}

// ---------------------------------------------------------------------------
// Kernel 3b: merge 4x10 candidates -> exact top-10 -> softmax -> blend.
// ---------------------------------------------------------------------------
__global__ __launch_bounds__(256) void match_merge(
    const float* __restrict__ topvw, const int* __restrict__ topiw,
    const float* __restrict__ memg, float* __restrict__ zmatch) {
  __shared__ float topw[8][10];
  __shared__ int topidx[8][10];
  const int t = threadIdx.x;
  const int rowbase = blockIdx.x * 8;

  if (t < 8) {
    float av[10];
    int ai[10];
#pragma unroll
    for (int i = 0; i < 10; ++i) { av[i] = -FLT_MAX; ai[i] = 0; }
    const size_t base = (size_t)(rowbase + t) * 40;
    for (int c = 0; c < 40; ++c) {
      float v = topvw[base + c];
      int m = topiw[base + c];
      if (v > av[9]) {
#pragma unroll
        for (int i = 0; i < 10; ++i) {
          if (v > av[i]) {
            float tv = av[i]; av[i] = v; v = tv;
            int ti = ai[i]; ai[i] = m; m = ti;
          }
        }
      }
    }
    float e_[10], s = 0.f;
#pragma unroll
    for (int k = 0; k < 10; ++k) { e_[k] = expf(av[k]); s += e_[k]; }
    float inv = 1.f / s;
#pragma unroll
    for (int k = 0; k < 10; ++k) { topw[t][k] = e_[k] * inv; topidx[t][k] = ai[k]; }
  }
  __syncthreads();
  for (int e = t; e < 8 * 128; e += TPB) {
    int r = e >> 7, d = e & 127;
    float o = 0.f;
#pragma unroll
    for (int k = 0; k < 10; ++k)
      o += topw[r][k] * memg[(size_t)topidx[r][k] * 128 + d];
    zmatch[(size_t)(rowbase + r) * 128 + d] = o;
  }
}

// ---------------------------------------------------------------------------
// Kernel 4: decoder FC GEMM (unchanged)
// ---------------------------------------------------------------------------
__global__ __launch_bounds__(256) void decfc_kernel(
    const float* __restrict__ zmatch, const float* __restrict__ fcw,
    const float* __restrict__ fcb, float* __restrict__ d0ws) {
  __shared__ __align__(16) float zt[64][128];
  const int t = threadIdx.x;
  const int c0 = blockIdx.x * 128;
  const int r0 = blockIdx.y * 64;
  {
    float4* zt4 = (float4*)&zt[0][0];
    const float4* zm4 = (const float4*)(zmatch + (size_t)r0 * 128);
    for (int e = t; e < 2048; e += TPB) zt4[e] = zm4[e];
  }
  __syncthreads();
  const int cg = (t & 31) * 4;
  const int rg = t >> 5;
  float acc[8][4] = {};
  for (int j = 0; j < 128; j += 4) {
    float4 wv[4];
#pragma unroll
    for (int c = 0; c < 4; ++c) {
      int col = c0 + cg + c;
      wv[c] = (col < 3136) ? *(const float4*)(fcw + (size_t)col * 128 + j)
                           : make_float4(0.f, 0.f, 0.f, 0.f);
    }
#pragma unroll
    for (int k = 0; k < 8; ++k) {
      float4 zv = *(const float4*)&zt[rg * 8 + k][j];
#pragma unroll
      for (int c = 0; c < 4; ++c)
        acc[k][c] += wv[c].x * zv.x + wv[c].y * zv.y + wv[c].z * zv.z + wv[c].w * zv.w;
    }
  }
#pragma unroll
  for (int k = 0; k < 8; ++k) {
    int row = r0 + rg * 8 + k;
#pragma unroll
    for (int c = 0; c < 4; ++c) {
      int col = c0 + cg + c;
      if (col < 3136) d0ws[(size_t)row * 3136 + col] = acc[k][c] + fcb[col];
    }
  }
}

// ---------------------------------------------------------------------------
// Kernel 5: fused decoder v2 (unchanged)
// ---------------------------------------------------------------------------
__global__ __launch_bounds__(256) void decoder_kernel(
    const float* __restrict__ d0g, const float* __restrict__ w1,
    const float* __restrict__ b1, const float* __restrict__ w2,
    const float* __restrict__ b2, const float* __restrict__ w3,
    const float* __restrict__ b3, const float* __restrict__ w4,
    const float* __restrict__ b4, float* __restrict__ out) {
  __shared__ float Buf1[3136];
  __shared__ float Buf2[8192];

  const int b = blockIdx.x;
  const int t = threadIdx.x;
  const int lane = t & 63;
  const int ph = __builtin_amdgcn_readfirstlane(t >> 6);
  const int pa = ph >> 1, pb = ph & 1;

  for (int e = t; e < 3136; e += TPB) Buf1[e] = d0g[(size_t)b * 3136 + e];
  for (int e = t; e < 8192; e += TPB) Buf2[e] = 0.f;
  __syncthreads();

  {
    const int i = lane / 7, j = lane % 7;
    const int p = 2 * i + pa, q = 2 * j + pb;
    int ih[2], iw[2];
    float mh[2], mw[2];
#pragma unroll
    for (int s = 0; s < 2; ++s) {
      int v = i + pa + s - 1;
      mh[s] = (v >= 0 && v <= 6) ? 1.f : 0.f;
      ih[s] = v < 0 ? 0 : (v > 6 ? 6 : v);
      int u = j + pb + s - 1;
      mw[s] = (u >= 0 && u <= 6) ? 1.f : 0.f;
      iw[s] = u < 0 ? 0 : (u > 6 ? 6 : u);
    }
    const float m00 = mh[0] * mw[0], m01 = mh[0] * mw[1];
    const float m10 = mh[1] * mw[0], m11 = mh[1] * mw[1];
    const int tb = pa * 4 + pb;
    const float* wA = w1 + (size_t)tb * 2048;
    const float* wB = w1 + (size_t)(tb + 2) * 2048;
    const float* wC = w1 + (size_t)(tb + 8) * 2048;
    const float* wD = w1 + (size_t)(tb + 10) * 2048;
#pragma unroll 1
    for (int half = 0; half < 2; ++half) {
      const int o0 = half * 16;
      float acc[16];
#pragma unroll
      for (int oo = 0; oo < 16; ++oo) acc[oo] = b1[o0 + oo];
#pragma unroll 2
      for (int c = 0; c < 64; ++c) {
        const float a00 = Buf1[c * 49 + ih[0] * 7 + iw[0]] * m00;
        const float a01 = Buf1[c * 49 + ih[0] * 7 + iw[1]] * m01;
        const float a10 = Buf1[c * 49 + ih[1] * 7 + iw[0]] * m10;
        const float a11 = Buf1[c * 49 + ih[1] * 7 + iw[1]] * m11;
        const int wb = c * 32 + o0;
#pragma unroll
        for (int oo = 0; oo < 16; ++oo)
          acc[oo] += a00 * wA[wb + oo] + a01 * wB[wb + oo] +
                     a10 * wC[wb + oo] + a11 * wD[wb + oo];
      }
      if (lane < 49) {
        const int widx = (p + 1) * 16 + (q + 1);
#pragma unroll
        for (int oo = 0; oo < 16; ++oo)
          Buf2[(o0 + oo) * 256 + widx] = fmaxf(acc[oo], 0.f);
      }
    }
  }
  __syncthreads();

  {
    const int oq = __builtin_amdgcn_readfirstlane((t >> 6) * 4);
    const int pc2 = lane & 15, prl = lane >> 4;
    const int cpc = pc2 < 14 ? pc2 : 13;
    float acc[4][4] = {};
#pragma unroll 1
    for (int c = 0; c < 32; ++c) {
      float wr[4][9];
#pragma unroll
      for (int oo = 0; oo < 4; ++oo)
#pragma unroll
        for (int u = 0; u < 9; ++u)
          wr[oo][u] = w2[((oq + oo) * 32 + c) * 9 + u];
#pragma unroll
      for (int k = 0; k < 4; ++k) {
        int row = k * 4 + prl;
        int crow = row < 14 ? row : 13;
        const float* hp = &Buf2[c * 256 + crow * 16 + cpc];
        float hv[9];
#pragma unroll
        for (int di = 0; di < 3; ++di)
#pragma unroll
          for (int dj = 0; dj < 3; ++dj) hv[di * 3 + dj] = hp[di * 16 + dj];
#pragma unroll
        for (int oo = 0; oo < 4; ++oo) {
          float s = acc[oo][k];
#pragma unroll
          for (int u = 0; u < 9; ++u) s += hv[u] * wr[oo][u];
          acc[oo][k] = s;
        }
      }
    }
    if (pc2 < 14) {
#pragma unroll
      for (int k = 0; k < 4; ++k) {
        int row = k * 4 + prl;
        if (row < 14) {
#pragma unroll
          for (int oo = 0; oo < 4; ++oo)
            Buf1[(oq + oo) * 196 + row * 14 + pc2] =
                fmaxf(acc[oo][k] + b2[oq + oo], 0.f);
        }
      }
    }
  }
  __syncthreads();
  for (int e = t; e < 7200; e += TPB) Buf2[e] = 0.f;
  __syncthreads();

  {
    const int tb = pa * 4 + pb;
    const float* wA = w3 + (size_t)tb * 128;
    const float* wB = w3 + (size_t)(tb + 2) * 128;
    const float* wC = w3 + (size_t)(tb + 8) * 128;
    const float* wD = w3 + (size_t)(tb + 10) * 128;
#pragma unroll 1
    for (int k = 0; k < 4; ++k) {
      const int px = lane + 64 * k;
      const int cpx = px < 196 ? px : 195;
      const int i = cpx / 14, j = cpx % 14;
      int ih[2], iw[2];
      float mh[2], mw[2];
#pragma unroll
      for (int s = 0; s < 2; ++s) {
        int v = i + pa + s - 1;
        mh[s] = (v >= 0 && v <= 13) ? 1.f : 0.f;
        ih[s] = v < 0 ? 0 : (v > 13 ? 13 : v);
        int u = j + pb + s - 1;
        mw[s] = (u >= 0 && u <= 13) ? 1.f : 0.f;
        iw[s] = u < 0 ? 0 : (u > 13 ? 13 : u);
      }
      const float m00 = mh[0] * mw[0], m01 = mh[0] * mw[1];
      const float m10 = mh[1] * mw[0], m11 = mh[1] * mw[1];
      float acc[8];
#pragma unroll
      for (int oo = 0; oo < 8; ++oo) acc[oo] = b3[oo];
#pragma unroll 2
      for (int c = 0; c < 16; ++c) {
        const float a00 = Buf1[c * 196 + ih[0] * 14 + iw[0]] * m00;
        const float a01 = Buf1[c * 196 + ih[0] * 14 + iw[1]] * m01;
        const float a10 = Buf1[c * 196 + ih[1] * 14 + iw[0]] * m10;
        const float a11 = Buf1[c * 196 + ih[1] * 14 + iw[1]] * m11;
        const int wb = c * 8;
#pragma unroll
        for (int oo = 0; oo < 8; ++oo)
          acc[oo] += a00 * wA[wb + oo] + a01 * wB[wb + oo] +
                     a10 * wC[wb + oo] + a11 * wD[wb + oo];
      }
      if (px < 196) {
        const int p = 2 * i + pa, q = 2 * j + pb;
        const int widx = (p + 1) * 30 + (q + 1);
#pragma unroll
        for (int oo = 0; oo < 8; ++oo)
          Buf2[oo * 900 + widx] = fmaxf(acc[oo], 0.f);
      }
    }
  }
  __syncthreads();

  for (int e = t; e < 784; e += TPB) {
    int p = e / 28, q = e - p * 28;
    float a = b4[0];
#pragma unroll
    for (int c = 0; c < 8; ++c) {
      const float* bp = &Buf2[c * 900 + p * 30 + q];
#pragma unroll
      for (int di = 0; di < 3; ++di)
#pragma unroll
        for (int dj = 0; dj < 3; ++dj)
          a += bp[di * 30 + dj] * w4[c * 9 + di * 3 + dj];
    }
    out[(size_t)b * 784 + e] = a;
  }
}

// ---------------------------------------------------------------------------
extern "C" void kernel_launch(void* const* d_in, const int* in_sizes, int n_in,
                              void* d_out, int out_size, void* d_ws,
                              size_t ws_size, hipStream_t stream) {
  const float* x      = (const float*)d_in[0];
  const float* ce_w1  = (const float*)d_in[1];
  const float* ce_b1  = (const float*)d_in[2];
  const float* ce_w2  = (const float*)d_in[3];
  const float* ce_b2  = (const float*)d_in[4];
  const float* ce_fcw = (const float*)d_in[5];
  const float* ce_fcb = (const float*)d_in[6];
  const float* ge_w1  = (const float*)d_in[7];
  const float* ge_b1  = (const float*)d_in[8];
  const float* ge_w2  = (const float*)d_in[9];
  const float* ge_b2  = (const float*)d_in[10];
  const float* ge_fcw = (const float*)d_in[11];
  const float* ge_fcb = (const float*)d_in[12];
  const float* memg   = (const float*)d_in[13];
  const float* dfcw   = (const float*)d_in[14];
  const float* dfcb   = (const float*)d_in[15];
  const float* d_w1   = (const float*)d_in[16];
  const float* d_b1   = (const float*)d_in[17];
  const float* d_w2   = (const float*)d_in[18];
  const float* d_b2   = (const float*)d_in[19];
  const float* d_w3   = (const float*)d_in[20];
  const float* d_b3   = (const float*)d_in[21];
  const float* d_w4   = (const float*)d_in[22];
  const float* d_b4   = (const float*)d_in[23];
  float* outp = (float*)d_out;

  // ws layout (floats): z[262144] | zmatch[262144] | invn[8192] |
  // frags[36864] | d0ws[2048*3136].
  // topv/topi (2048*40 each) alias the d0ws region (disjoint lifetimes).
  float* ws     = (float*)d_ws;
  float* z      = ws;
  float* zmatch = ws + 262144;
  float* invn   = ws + 524288;
  float* frags  = ws + 532480;
  float* d0ws   = ws + 532480 + 36864;
  float* topvw  = d0ws;
  int*   topiw  = (int*)(d0ws + 81920);

  prep_bfrags<<<144, 64, 0, stream>>>(ce_w2, ge_w2, frags);
  norm_kernel<<<2048, TPB, 0, stream>>>(memg, invn);
  encoders_fused<<<4096, TPB, 0, stream>>>(x, ce_w1, ce_b1, ce_b2, ce_fcw,
                                           ce_fcb, ge_w1, ge_b1, ge_b2, ge_fcw,
                                           ge_fcb, frags, z);
  match_part<<<dim3(256, 4), TPB, 0, stream>>>(z, memg, invn, topvw, topiw);
  match_merge<<<256, TPB, 0, stream>>>(topvw, topiw, memg, zmatch);
  decfc_kernel<<<dim3(25, 32), TPB, 0, stream>>>(zmatch, dfcw, dfcb, d0ws);
  decoder_kernel<<<2048, TPB, 0, stream>>>(d0ws, d_w1, d_b1, d_w2, d_b2, d_w3,
                                           d_b3, d_w4, d_b4, outp);
}

// Round 8
// 840.037 us; speedup vs baseline: 1.3041x; 1.3041x over previous
//
#include <hip/hip_runtime.h>
#include <cfloat>
#include <cmath>

#define TPB 256

typedef _Float16 half8 __attribute__((ext_vector_type(8)));
typedef float floatx16 __attribute__((ext_vector_type(16)));

__device__ __forceinline__ float wave_reduce_sum(float v) {
#pragma unroll
  for (int off = 32; off > 0; off >>= 1) v += __shfl_xor(v, off, 64);
  return v;
}

// ---------------------------------------------------------------------------
// Kernel 0a: build conv2 B-fragments (2-part f16 split) for both encoders.
// ---------------------------------------------------------------------------
__global__ __launch_bounds__(64) void prep_bfrags(
    const float* __restrict__ ce_w2, const float* __restrict__ ge_w2,
    float* __restrict__ frags) {
  const int blk = blockIdx.x;  // 144 = 2 enc x 72 frags
  const int enc = blk / 72;
  const int frag = blk % 72;
  const int ks = frag >> 2, part = (frag >> 1) & 1, nt = frag & 1;
  const int tap = ks >> 1, half = ks & 1;
  const int lane = threadIdx.x;
  const float* w2 = enc ? ge_w2 : ce_w2;
  const int n = nt * 32 + (lane & 31);
  const int cb = half * 16 + (lane >> 5) * 8;
  half8 out;
#pragma unroll
  for (int j = 0; j < 8; ++j) {
    float v = w2[(n * 32 + cb + j) * 9 + tap];
    _Float16 h = (_Float16)v;
    out[j] = (part == 0) ? h : (_Float16)((v - (float)h) * 4096.f);
  }
  *(half8*)((char*)frags + ((size_t)blk * 64 + lane) * 16) = out;
}

// ---------------------------------------------------------------------------
// Kernel 0b: build decoder deconv1 B-fragments (single f16).
// 64 blocks = 4 phases x 16 ksteps. B[k][n] = w1[kh][kw][c][n],
// k = (c & group struct): c = kk*16 + kg*8 + j, (s,t) = kstep>>2.
// ---------------------------------------------------------------------------
__global__ __launch_bounds__(64) void prep_dec1(
    const float* __restrict__ w1, float* __restrict__ frags) {
  const int blk = blockIdx.x;
  const int phase = blk >> 4, ks = blk & 15;
  const int pa = phase >> 1, pb = phase & 1;
  const int st = ks >> 2, kk = ks & 3;
  const int s = st >> 1, tt = st & 1;
  const int lane = threadIdx.x;
  const int kg = lane >> 5, n = lane & 31;
  const int tap = (pa + 2 * s) * 4 + (pb + 2 * tt);
  half8 o;
#pragma unroll
  for (int j = 0; j < 8; ++j) {
    int c = kk * 16 + kg * 8 + j;
    o[j] = (_Float16)w1[tap * 2048 + c * 32 + n];
  }
  *(half8*)((char*)frags + ((size_t)blk * 64 + lane) * 16) = o;
}

// ---------------------------------------------------------------------------
// Kernel 1: memory row inverse norms
// ---------------------------------------------------------------------------
__global__ __launch_bounds__(256) void norm_kernel(
    const float* __restrict__ memg, float* __restrict__ invn) {
  const int wv = threadIdx.x >> 6, lane = threadIdx.x & 63;
  const int row = blockIdx.x * 4 + wv;
  const float* r = memg + (size_t)row * 128;
  float a = r[lane], b = r[lane + 64];
  float s = wave_reduce_sum(a * a + b * b);
  if (lane == 0) invn[row] = 1.f / fmaxf(sqrtf(s), 1e-12f);
}

// ---------------------------------------------------------------------------
// Kernel 2: MFMA encoder (r6 version — proven 320 us, no spills).
// ---------------------------------------------------------------------------
template <int S, bool CENTER>
__device__ __forceinline__ void encoder_body(
    char* smem, const float* __restrict__ x, const float* __restrict__ w1,
    const float* __restrict__ b1, const float* __restrict__ b2,
    const float* __restrict__ fcw, const float* __restrict__ fcb,
    const float* __restrict__ bfrag, float* __restrict__ zout, int zoff,
    int b) {
  constexpr int SP = S + 2;
  constexpr int NBANDS = (S == 28) ? 3 : 2;  // bands {10,10,8} / {10,4}
  constexpr int RMAX = 12;
  constexpr int NPIX = RMAX * SP;
  constexpr int GSTB = NPIX * 16;
  constexpr int PSTB = 4 * GSTB;

  char* h1s = smem;
  float* xs = (float*)(smem + 2 * PSTB);
  float* w1s = xs + SP * SP;
  float(*featp)[64] = (float(*)[64])(w1s + 288);

  const int t = threadIdx.x;
  const int lane = t & 63;
  const int wv = t >> 6;

  for (int e = t; e < SP * SP; e += TPB) xs[e] = 0.f;
  for (int e = t; e < 288; e += TPB) w1s[e] = w1[e];
  __syncthreads();
  const float* xb = x + (size_t)b * 784 + (CENTER ? (7 * 28 + 7) : 0);
  for (int e = t; e < S * S; e += TPB) {
    int i = e / S, j = e - i * S;
    xs[(i + 1) * SP + (j + 1)] = xb[i * 28 + j];
  }

  float sp0 = 0.f, sp1 = 0.f;
  const float bias0 = b2[lane & 31];
  const float bias1 = b2[32 + (lane & 31)];
  const int gOff = (lane >> 5) * GSTB;
  const char* bgbase = (const char*)bfrag + lane * 16;

#pragma unroll
  for (int band = 0; band < NBANDS; ++band) {
    const int BH_ = (S == 28) ? ((band < 2) ? 10 : 8) : ((band == 0) ? 10 : 4);
    const int b0 = band * 10;
    const int LIMIT = BH_ * S;
    const int MTB = (LIMIT + 31) / 32;
    const int NBLK2 = (MTB + 1) / 2;

    __syncthreads();
    for (int e = t; e < 4 * NPIX; e += TPB) {
      int g = e / NPIX;
      int pix = e - g * NPIX;
      int lr = pix / SP;
      int cw = pix - lr * SP;
      int gr = b0 - 1 + lr;
      int ebase = g * GSTB + pix * 16;
      half8 hi8 = {}, lo8 = {};
      if (gr >= 0 && gr < S && cw >= 1 && cw <= S) {
        float xv[9];
#pragma unroll
        for (int di = 0; di < 3; ++di)
#pragma unroll
          for (int dj = 0; dj < 3; ++dj)
            xv[di * 3 + dj] = xs[(gr + di) * SP + (cw - 1 + dj)];
#pragma unroll
        for (int u = 0; u < 8; ++u) {
          int ch = g * 8 + u;
          float a = b1[ch];
#pragma unroll
          for (int v = 0; v < 9; ++v) a += xv[v] * w1s[ch * 9 + v];
          a = fmaxf(a, 0.f);
          _Float16 h = (_Float16)a;
          hi8[u] = h;
          lo8[u] = (_Float16)((a - (float)h) * 4096.f);
        }
      }
      *(half8*)(h1s + ebase) = hi8;
      *(half8*)(h1s + PSTB + ebase) = lo8;
    }
    __syncthreads();
    for (int mblk = wv; mblk < NBLK2; mblk += 4) {
      const int Mt0 = mblk * 2;
      floatx16 acc[2][2][2] = {};
      int pixB[2];
#pragma unroll
      for (int im = 0; im < 2; ++im) {
        int px = (Mt0 + im) * 32 + (lane & 31);
        px = px < LIMIT ? px : LIMIT - 1;
        int r = px / S;
        int cc = px - r * S;
        pixB[im] = (r * SP + cc) * 16;
      }
#pragma unroll 3
      for (int tap = 0; tap < 9; ++tap) {
        const int di = tap / 3, dj = tap - di * 3;
        const int offT = (di * SP + dj) * 16;
#pragma unroll
        for (int half = 0; half < 2; ++half) {
          const int ks = tap * 2 + half;
          const char* bp = bgbase + ks * 4096;
          const int offA = offT + gOff + half * (2 * GSTB);
          half8 ah0 = *(const half8*)(h1s + pixB[0] + offA);
          half8 al0 = *(const half8*)(h1s + PSTB + pixB[0] + offA);
          half8 ah1 = *(const half8*)(h1s + pixB[1] + offA);
          half8 al1 = *(const half8*)(h1s + PSTB + pixB[1] + offA);
          {  // nt = 0
            half8 bh = *(const half8*)(bp);
            half8 bl = *(const half8*)(bp + 2048);
            acc[0][0][0] = __builtin_amdgcn_mfma_f32_32x32x16_f16(
                ah0, bh, acc[0][0][0], 0, 0, 0);
            acc[0][0][1] = __builtin_amdgcn_mfma_f32_32x32x16_f16(
                ah0, bl, acc[0][0][1], 0, 0, 0);
            acc[0][0][1] = __builtin_amdgcn_mfma_f32_32x32x16_f16(
                al0, bh, acc[0][0][1], 0, 0, 0);
            acc[1][0][0] = __builtin_amdgcn_mfma_f32_32x32x16_f16(
                ah1, bh, acc[1][0][0], 0, 0, 0);
            acc[1][0][1] = __builtin_amdgcn_mfma_f32_32x32x16_f16(
                ah1, bl, acc[1][0][1], 0, 0, 0);
            acc[1][0][1] = __builtin_amdgcn_mfma_f32_32x32x16_f16(
                al1, bh, acc[1][0][1], 0, 0, 0);
          }
          {  // nt = 1
            half8 bh = *(const half8*)(bp + 1024);
            half8 bl = *(const half8*)(bp + 3072);
            acc[0][1][0] = __builtin_amdgcn_mfma_f32_32x32x16_f16(
                ah0, bh, acc[0][1][0], 0, 0, 0);
            acc[0][1][1] = __builtin_amdgcn_mfma_f32_32x32x16_f16(
                ah0, bl, acc[0][1][1], 0, 0, 0);
            acc[0][1][1] = __builtin_amdgcn_mfma_f32_32x32x16_f16(
                al0, bh, acc[0][1][1], 0, 0, 0);
            acc[1][1][0] = __builtin_amdgcn_mfma_f32_32x32x16_f16(
                ah1, bh, acc[1][1][0], 0, 0, 0);
            acc[1][1][1] = __builtin_amdgcn_mfma_f32_32x32x16_f16(
                ah1, bl, acc[1][1][1], 0, 0, 0);
            acc[1][1][1] = __builtin_amdgcn_mfma_f32_32x32x16_f16(
                al1, bh, acc[1][1][1], 0, 0, 0);
          }
        }
      }
#pragma unroll
      for (int im = 0; im < 2; ++im)
#pragma unroll
        for (int reg = 0; reg < 16; ++reg) {
          int row = (reg & 3) + 8 * (reg >> 2) + 4 * (lane >> 5);
          int p = (Mt0 + im) * 32 + row;
          if (p < LIMIT) {
            float v0 =
                acc[im][0][0][reg] + acc[im][0][1][reg] * (1.f / 4096.f) + bias0;
            float v1 =
                acc[im][1][0][reg] + acc[im][1][1][reg] * (1.f / 4096.f) + bias1;
            sp0 += fmaxf(v0, 0.f);
            sp1 += fmaxf(v1, 0.f);
          }
        }
    }
  }
  sp0 += __shfl_xor(sp0, 32);
  sp1 += __shfl_xor(sp1, 32);
  if (lane < 32) {
    featp[wv][lane] = sp0;
    featp[wv][32 + lane] = sp1;
  }
  __syncthreads();
  if (t < 64)
    featp[0][t] = (featp[0][t] + featp[1][t] + featp[2][t] + featp[3][t]) *
                  (1.f / (S * S));
  __syncthreads();
  if (t < 64) {
    float s = 0.f;
#pragma unroll
    for (int i = 0; i < 64; ++i) s += featp[0][i] * fcw[t * 64 + i];
    zout[(size_t)b * 128 + zoff + t] = s + fcb[t];
  }
}

// LDS: 2*PSTB(S=28)=46080 + xs 3600 + w1s 1152 + featp 1024 = 51856 B
// -> 3 blocks/CU.
__global__ __launch_bounds__(256, 3) void encoders_fused(
    const float* __restrict__ x, const float* __restrict__ ce_w1,
    const float* __restrict__ ce_b1, const float* __restrict__ ce_b2,
    const float* __restrict__ ce_fcw, const float* __restrict__ ce_fcb,
    const float* __restrict__ ge_w1, const float* __restrict__ ge_b1,
    const float* __restrict__ ge_b2, const float* __restrict__ ge_fcw,
    const float* __restrict__ ge_fcb, const float* __restrict__ frags,
    float* __restrict__ z) {
  __shared__ __align__(16) char smem[51856];
  if (blockIdx.x < 2048)
    encoder_body<28, false>(smem, x, ge_w1, ge_b1, ge_b2, ge_fcw, ge_fcb,
                            frags + 18432, z, 64, blockIdx.x);
  else
    encoder_body<14, true>(smem, x, ce_w1, ce_b1, ce_b2, ce_fcw, ce_fcb, frags,
                           z, 0, blockIdx.x - 2048);
}

// ---------------------------------------------------------------------------
// Kernel 3a: partial match. Grid (256 z-groups, 4 mem-quarters).
// ---------------------------------------------------------------------------
__global__ __launch_bounds__(256) void match_part(
    const float* __restrict__ z, const float* __restrict__ memg,
    const float* __restrict__ invn, float* __restrict__ topvw,
    int* __restrict__ topiw) {
  __shared__ __align__(16) float zs[8][128];
  __shared__ float qv[8][512];
  __shared__ int qi[8][512];
  __shared__ int qn[8];
  __shared__ float rowmin[8];

  const int t = threadIdx.x;
  const int rowbase = blockIdx.x * 8;
  const int mbase = blockIdx.y * 2048;

  for (int e = t; e < 8 * 128; e += TPB) {
    int r = e >> 7, j = e & 127;
    zs[r][j] = z[(size_t)(rowbase + r) * 128 + j];
  }
  if (t < 8) { qn[t] = 0; rowmin[t] = -FLT_MAX; }
  __syncthreads();
  {
    int wv = t >> 6, lane = t & 63;
#pragma unroll
    for (int h = 0; h < 2; ++h) {
      int r = wv + h * 4;
      float a = zs[r][lane], b = zs[r][lane + 64];
      float s = wave_reduce_sum(a * a + b * b);
      float inv = 1.f / fmaxf(sqrtf(s), 1e-12f);
      zs[r][lane] = a * inv;
      zs[r][lane + 64] = b * inv;
    }
  }
  __syncthreads();

  float av[10];
  int ai[10];
#pragma unroll
  for (int i = 0; i < 10; ++i) { av[i] = -FLT_MAX; ai[i] = 0; }

  for (int mt = 0; mt < 4; ++mt) {
    int m0 = mbase + mt * 512 + t;
    float acc0[8] = {}, acc1[8] = {};
    const float4* mr0 = (const float4*)(memg + (size_t)m0 * 128);
    const float4* mr1 = (const float4*)(memg + (size_t)(m0 + 256) * 128);
#pragma unroll 4
    for (int jq = 0; jq < 32; ++jq) {
      float4 a0 = mr0[jq], a1 = mr1[jq];
#pragma unroll
      for (int r = 0; r < 8; ++r) {
        float4 zv = ((const float4*)zs[r])[jq];
        acc0[r] += a0.x * zv.x + a0.y * zv.y + a0.z * zv.z + a0.w * zv.w;
        acc1[r] += a1.x * zv.x + a1.y * zv.y + a1.z * zv.z + a1.w * zv.w;
      }
    }
    float i0 = invn[m0], i1 = invn[m0 + 256];
#pragma unroll
    for (int r = 0; r < 8; ++r) {
      float rm = rowmin[r];
      float v0 = acc0[r] * i0;
      if (v0 > rm) {
        int k = atomicAdd(&qn[r], 1);
        qv[r][k] = v0; qi[r][k] = m0;
      }
      float v1 = acc1[r] * i1;
      if (v1 > rm) {
        int k = atomicAdd(&qn[r], 1);
        qv[r][k] = v1; qi[r][k] = m0 + 256;
      }
    }
    __syncthreads();
    if (t < 8) {
      int n = qn[t];
      for (int k = 0; k < n; ++k) {
        float v = qv[t][k];
        int m = qi[t][k];
        if (v > av[9]) {
#pragma unroll
          for (int i = 0; i < 10; ++i) {
            if (v > av[i]) {
              float tv = av[i]; av[i] = v; v = tv;
              int ti = ai[i]; ai[i] = m; m = ti;
            }
          }
        }
      }
      qn[t] = 0;
      rowmin[t] = av[9];
    }
    __syncthreads();
  }

  if (t < 8) {
    const size_t base = (size_t)(rowbase + t) * 40 + blockIdx.y * 10;
#pragma unroll
    for (int k = 0; k < 10; ++k) {
      topvw[base + k] = av[k];
      topiw[base + k] = ai[k];
    }
  }
}

// ---------------------------------------------------------------------------
// Kernel 3b: merge 4x10 candidates -> exact top-10 -> softmax -> blend.
// ---------------------------------------------------------------------------
__global__ __launch_bounds__(256) void match_merge(
    const float* __restrict__ topvw, const int* __restrict__ topiw,
    const float* __restrict__ memg, float* __restrict__ zmatch) {
  __shared__ float topw[8][10];
  __shared__ int topidx[8][10];
  const int t = threadIdx.x;
  const int rowbase = blockIdx.x * 8;

  if (t < 8) {
    float av[10];
    int ai[10];
#pragma unroll
    for (int i = 0; i < 10; ++i) { av[i] = -FLT_MAX; ai[i] = 0; }
    const size_t base = (size_t)(rowbase + t) * 40;
    for (int c = 0; c < 40; ++c) {
      float v = topvw[base + c];
      int m = topiw[base + c];
      if (v > av[9]) {
#pragma unroll
        for (int i = 0; i < 10; ++i) {
          if (v > av[i]) {
            float tv = av[i]; av[i] = v; v = tv;
            int ti = ai[i]; ai[i] = m; m = ti;
          }
        }
      }
    }
    float e_[10], s = 0.f;
#pragma unroll
    for (int k = 0; k < 10; ++k) { e_[k] = expf(av[k]); s += e_[k]; }
    float inv = 1.f / s;
#pragma unroll
    for (int k = 0; k < 10; ++k) { topw[t][k] = e_[k] * inv; topidx[t][k] = ai[k]; }
  }
  __syncthreads();
  for (int e = t; e < 8 * 128; e += TPB) {
    int r = e >> 7, d = e & 127;
    float o = 0.f;
#pragma unroll
    for (int k = 0; k < 10; ++k)
      o += topw[r][k] * memg[(size_t)topidx[r][k] * 128 + d];
    zmatch[(size_t)(rowbase + r) * 128 + d] = o;
  }
}

// ---------------------------------------------------------------------------
// Kernel 4: decoder FC GEMM (unchanged)
// ---------------------------------------------------------------------------
__global__ __launch_bounds__(256) void decfc_kernel(
    const float* __restrict__ zmatch, const float* __restrict__ fcw,
    const float* __restrict__ fcb, float* __restrict__ d0ws) {
  __shared__ __align__(16) float zt[64][128];
  const int t = threadIdx.x;
  const int c0 = blockIdx.x * 128;
  const int r0 = blockIdx.y * 64;
  {
    float4* zt4 = (float4*)&zt[0][0];
    const float4* zm4 = (const float4*)(zmatch + (size_t)r0 * 128);
    for (int e = t; e < 2048; e += TPB) zt4[e] = zm4[e];
  }
  __syncthreads();
  const int cg = (t & 31) * 4;
  const int rg = t >> 5;
  float acc[8][4] = {};
  for (int j = 0; j < 128; j += 4) {
    float4 wv[4];
#pragma unroll
    for (int c = 0; c < 4; ++c) {
      int col = c0 + cg + c;
      wv[c] = (col < 3136) ? *(const float4*)(fcw + (size_t)col * 128 + j)
                           : make_float4(0.f, 0.f, 0.f, 0.f);
    }
#pragma unroll
    for (int k = 0; k < 8; ++k) {
      float4 zv = *(const float4*)&zt[rg * 8 + k][j];
#pragma unroll
      for (int c = 0; c < 4; ++c)
        acc[k][c] += wv[c].x * zv.x + wv[c].y * zv.y + wv[c].z * zv.z + wv[c].w * zv.w;
    }
  }
#pragma unroll
  for (int k = 0; k < 8; ++k) {
    int row = r0 + rg * 8 + k;
#pragma unroll
    for (int c = 0; c < 4; ++c) {
      int col = c0 + cg + c;
      if (col < 3136) d0ws[(size_t)row * 3136 + col] = acc[k][c] + fcb[col];
    }
  }
}

// ---------------------------------------------------------------------------
// Kernel 5: decoder v3 — deconv1 via f16 MFMA (direct channel-last reads,
// no im2col). LDS regions: A [0,12544): d0f f16 (10368B) then d2 fp32
// [16][196]; B [12544, +32896): d1 padded fp32 [32][257] (stride 257 kills
// the o-indexed bank conflicts). Rest of the pipeline = r1 verified code.
// ---------------------------------------------------------------------------
__global__ __launch_bounds__(256) void decoder_kernel(
    const float* __restrict__ d0g, const float* __restrict__ w1,
    const float* __restrict__ b1, const float* __restrict__ w2,
    const float* __restrict__ b2, const float* __restrict__ w3,
    const float* __restrict__ b3, const float* __restrict__ w4,
    const float* __restrict__ b4, const float* __restrict__ dec1frags,
    float* __restrict__ out) {
  __shared__ __align__(16) char dsm[12544 + 32896];
  char* d0f = dsm;                          // f16 [8 grp][81 pix][16B]
  float* d2 = (float*)dsm;                  // later: fp32 [16][196]
  float* Buf2 = (float*)(dsm + 12544);      // fp32 [32][257] d1; later d3

  const int b = blockIdx.x;
  const int t = threadIdx.x;
  const int lane = t & 63;
  const int wv = t >> 6;

  // stage d0f (halo-padded 9x9, channel-last groups of 8) + zero d1
  for (int e = t; e < 648; e += TPB) {
    int g = e / 81, pix = e - g * 81;
    int ih = pix / 9 - 1, iw = pix % 9 - 1;
    half8 hv = {};
    if (ih >= 0 && ih < 7 && iw >= 0 && iw < 7) {
      const float* src = d0g + (size_t)b * 3136 + g * 8 * 49 + ih * 7 + iw;
#pragma unroll
      for (int u = 0; u < 8; ++u) hv[u] = (_Float16)src[u * 49];
    }
    *(half8*)(d0f + e * 16) = hv;
  }
  for (int e = t; e < 8224; e += TPB) Buf2[e] = 0.f;
  __syncthreads();

  // ---- deconv1 MFMA: wave = phase (pa,pb). 4 (s,t)-GEMMs, K=64 each.
  {
    const int pa = wv >> 1, pb = wv & 1;
    const int kg = lane >> 5, o = lane & 31;
    const char* bg = (const char*)dec1frags + wv * 16384 + lane * 16;
    int pxa[2][4];
#pragma unroll
    for (int im = 0; im < 2; ++im) {
      int px = im * 32 + o;
      px = px < 49 ? px : 48;
      int i = px / 7, j2 = px - i * 7;
#pragma unroll
      for (int st = 0; st < 4; ++st) {
        int s = st >> 1, tt = st & 1;
        pxa[im][st] = ((i + pa + s) * 9 + (j2 + pb + tt)) * 16;
      }
    }
    floatx16 acc0 = {}, acc1 = {};
    half8 nb = *(const half8*)(bg);
#pragma unroll
    for (int ks = 0; ks < 16; ++ks) {
      half8 bf = nb;
      if (ks < 15) nb = *(const half8*)(bg + (ks + 1) * 1024);
      const int gbase = (((ks & 3) * 2 + kg) * 81) * 16;
      half8 a0 = *(const half8*)(d0f + gbase + pxa[0][ks >> 2]);
      half8 a1 = *(const half8*)(d0f + gbase + pxa[1][ks >> 2]);
      acc0 = __builtin_amdgcn_mfma_f32_32x32x16_f16(a0, bf, acc0, 0, 0, 0);
      acc1 = __builtin_amdgcn_mfma_f32_32x32x16_f16(a1, bf, acc1, 0, 0, 0);
    }
    const float bias = b1[o];
#pragma unroll
    for (int im = 0; im < 2; ++im) {
      const floatx16& ac = im ? acc1 : acc0;
#pragma unroll
      for (int reg = 0; reg < 16; ++reg) {
        int row = (reg & 3) + 8 * (reg >> 2) + 4 * kg;
        int px = im * 32 + row;
        if (px < 49) {
          int i = px / 7, j2 = px - i * 7;
          int p = 2 * i + pa, q = 2 * j2 + pb;
          Buf2[o * 257 + (p + 1) * 16 + (q + 1)] = fmaxf(ac[reg] + bias, 0.f);
        }
      }
    }
  }
  __syncthreads();

  // ---- conv2: d1[32][14][14] -> d2[16][196]; wave = o-quad
  {
    const int oq = __builtin_amdgcn_readfirstlane((t >> 6) * 4);
    const int pc2 = lane & 15, prl = lane >> 4;
    const int cpc = pc2 < 14 ? pc2 : 13;
    float acc[4][4] = {};
#pragma unroll 1
    for (int c = 0; c < 32; ++c) {
      float wr[4][9];
#pragma unroll
      for (int oo = 0; oo < 4; ++oo)
#pragma unroll
        for (int u = 0; u < 9; ++u)
          wr[oo][u] = w2[((oq + oo) * 32 + c) * 9 + u];
#pragma unroll
      for (int k = 0; k < 4; ++k) {
        int row = k * 4 + prl;
        int crow = row < 14 ? row : 13;
        const float* hp = &Buf2[c * 257 + crow * 16 + cpc];
        float hv[9];
#pragma unroll
        for (int di = 0; di < 3; ++di)
#pragma unroll
          for (int dj = 0; dj < 3; ++dj) hv[di * 3 + dj] = hp[di * 16 + dj];
#pragma unroll
        for (int oo = 0; oo < 4; ++oo) {
          float s = acc[oo][k];
#pragma unroll
          for (int u = 0; u < 9; ++u) s += hv[u] * wr[oo][u];
          acc[oo][k] = s;
        }
      }
    }
    if (pc2 < 14) {
#pragma unroll
      for (int k = 0; k < 4; ++k) {
        int row = k * 4 + prl;
        if (row < 14) {
#pragma unroll
          for (int oo = 0; oo < 4; ++oo)
            d2[(oq + oo) * 196 + row * 14 + pc2] =
                fmaxf(acc[oo][k] + b2[oq + oo], 0.f);
        }
      }
    }
  }
  __syncthreads();
  for (int e = t; e < 7200; e += TPB) Buf2[e] = 0.f;  // d3 padded [8][30][30]
  __syncthreads();

  // ---- deconv2: d2[16][14][14] -> d3[8][28][28]; wave = phase
  {
    const int ph = __builtin_amdgcn_readfirstlane(t >> 6);
    const int pa = ph >> 1, pb = ph & 1;
    const int tb = pa * 4 + pb;
    const float* wA = w3 + (size_t)tb * 128;
    const float* wB = w3 + (size_t)(tb + 2) * 128;
    const float* wC = w3 + (size_t)(tb + 8) * 128;
    const float* wD = w3 + (size_t)(tb + 10) * 128;
#pragma unroll 1
    for (int k = 0; k < 4; ++k) {
      const int px = lane + 64 * k;
      const int cpx = px < 196 ? px : 195;
      const int i = cpx / 14, j = cpx % 14;
      int ih[2], iw[2];
      float mh[2], mw[2];
#pragma unroll
      for (int s = 0; s < 2; ++s) {
        int v = i + pa + s - 1;
        mh[s] = (v >= 0 && v <= 13) ? 1.f : 0.f;
        ih[s] = v < 0 ? 0 : (v > 13 ? 13 : v);
        int u = j + pb + s - 1;
        mw[s] = (u >= 0 && u <= 13) ? 1.f : 0.f;
        iw[s] = u < 0 ? 0 : (u > 13 ? 13 : u);
      }
      const float m00 = mh[0] * mw[0], m01 = mh[0] * mw[1];
      const float m10 = mh[1] * mw[0], m11 = mh[1] * mw[1];
      float acc[8];
#pragma unroll
      for (int oo = 0; oo < 8; ++oo) acc[oo] = b3[oo];
#pragma unroll 2
      for (int c = 0; c < 16; ++c) {
        const float a00 = d2[c * 196 + ih[0] * 14 + iw[0]] * m00;
        const float a01 = d2[c * 196 + ih[0] * 14 + iw[1]] * m01;
        const float a10 = d2[c * 196 + ih[1] * 14 + iw[0]] * m10;
        const float a11 = d2[c * 196 + ih[1] * 14 + iw[1]] * m11;
        const int wb = c * 8;
#pragma unroll
        for (int oo = 0; oo < 8; ++oo)
          acc[oo] += a00 * wA[wb + oo] + a01 * wB[wb + oo] +
                     a10 * wC[wb + oo] + a11 * wD[wb + oo];
      }
      if (px < 196) {
        const int p = 2 * i + pa, q = 2 * j + pb;
        const int widx = (p + 1) * 30 + (q + 1);
#pragma unroll
        for (int oo = 0; oo < 8; ++oo)
          Buf2[oo * 900 + widx] = fmaxf(acc[oo], 0.f);
      }
    }
  }
  __syncthreads();

  // ---- final conv: d3[8][28][28] -> out[1][28][28]
  for (int e = t; e < 784; e += TPB) {
    int p = e / 28, q = e - p * 28;
    float a = b4[0];
#pragma unroll
    for (int c = 0; c < 8; ++c) {
      const float* bp = &Buf2[c * 900 + p * 30 + q];
#pragma unroll
      for (int di = 0; di < 3; ++di)
#pragma unroll
        for (int dj = 0; dj < 3; ++dj)
          a += bp[di * 30 + dj] * w4[c * 9 + di * 3 + dj];
    }
    out[(size_t)b * 784 + e] = a;
  }
}

// ---------------------------------------------------------------------------
extern "C" void kernel_launch(void* const* d_in, const int* in_sizes, int n_in,
                              void* d_out, int out_size, void* d_ws,
                              size_t ws_size, hipStream_t stream) {
  const float* x      = (const float*)d_in[0];
  const float* ce_w1  = (const float*)d_in[1];
  const float* ce_b1  = (const float*)d_in[2];
  const float* ce_w2  = (const float*)d_in[3];
  const float* ce_b2  = (const float*)d_in[4];
  const float* ce_fcw = (const float*)d_in[5];
  const float* ce_fcb = (const float*)d_in[6];
  const float* ge_w1  = (const float*)d_in[7];
  const float* ge_b1  = (const float*)d_in[8];
  const float* ge_w2  = (const float*)d_in[9];
  const float* ge_b2  = (const float*)d_in[10];
  const float* ge_fcw = (const float*)d_in[11];
  const float* ge_fcb = (const float*)d_in[12];
  const float* memg   = (const float*)d_in[13];
  const float* dfcw   = (const float*)d_in[14];
  const float* dfcb   = (const float*)d_in[15];
  const float* d_w1   = (const float*)d_in[16];
  const float* d_b1   = (const float*)d_in[17];
  const float* d_w2   = (const float*)d_in[18];
  const float* d_b2   = (const float*)d_in[19];
  const float* d_w3   = (const float*)d_in[20];
  const float* d_b3   = (const float*)d_in[21];
  const float* d_w4   = (const float*)d_in[22];
  const float* d_b4   = (const float*)d_in[23];
  float* outp = (float*)d_out;

  // ws layout (floats): z[262144] | zmatch[262144] | invn[8192] |
  // frags[36864] | dec1frags[16384] | d0ws[2048*3136].
  // topv/topi (2048*40 each) alias the d0ws region (disjoint lifetimes).
  float* ws        = (float*)d_ws;
  float* z         = ws;
  float* zmatch    = ws + 262144;
  float* invn      = ws + 524288;
  float* frags     = ws + 532480;
  float* dec1frags = ws + 532480 + 36864;
  float* d0ws      = ws + 532480 + 36864 + 16384;
  float* topvw     = d0ws;
  int*   topiw     = (int*)(d0ws + 81920);

  prep_bfrags<<<144, 64, 0, stream>>>(ce_w2, ge_w2, frags);
  prep_dec1<<<64, 64, 0, stream>>>(d_w1, dec1frags);
  norm_kernel<<<2048, TPB, 0, stream>>>(memg, invn);
  encoders_fused<<<4096, TPB, 0, stream>>>(x, ce_w1, ce_b1, ce_b2, ce_fcw,
                                           ce_fcb, ge_w1, ge_b1, ge_b2, ge_fcw,
                                           ge_fcb, frags, z);
  match_part<<<dim3(256, 4), TPB, 0, stream>>>(z, memg, invn, topvw, topiw);
  match_merge<<<256, TPB, 0, stream>>>(topvw, topiw, memg, zmatch);
  decfc_kernel<<<dim3(25, 32), TPB, 0, stream>>>(zmatch, dfcw, dfcb, d0ws);
  decoder_kernel<<<2048, TPB, 0, stream>>>(d0ws, d_w1, d_b1, d_w2, d_b2, d_w3,
                                           d_b3, d_w4, d_b4, dec1frags, outp);
}

// Round 9
// 711.716 us; speedup vs baseline: 1.5392x; 1.1803x over previous
//
#include <hip/hip_runtime.h>
#include <cfloat>
#include <cmath>

#define TPB 256

typedef _Float16 half8 __attribute__((ext_vector_type(8)));
typedef float floatx16 __attribute__((ext_vector_type(16)));
typedef float floatx4 __attribute__((ext_vector_type(4)));

__device__ __forceinline__ float wave_reduce_sum(float v) {
#pragma unroll
  for (int off = 32; off > 0; off >>= 1) v += __shfl_xor(v, off, 64);
  return v;
}

// ---------------------------------------------------------------------------
// Kernel 0a: encoder conv2 B-fragments (2-part f16 split).
// ---------------------------------------------------------------------------
__global__ __launch_bounds__(64) void prep_bfrags(
    const float* __restrict__ ce_w2, const float* __restrict__ ge_w2,
    float* __restrict__ frags) {
  const int blk = blockIdx.x;  // 144 = 2 enc x 72 frags
  const int enc = blk / 72;
  const int frag = blk % 72;
  const int ks = frag >> 2, part = (frag >> 1) & 1, nt = frag & 1;
  const int tap = ks >> 1, half = ks & 1;
  const int lane = threadIdx.x;
  const float* w2 = enc ? ge_w2 : ce_w2;
  const int n = nt * 32 + (lane & 31);
  const int cb = half * 16 + (lane >> 5) * 8;
  half8 out;
#pragma unroll
  for (int j = 0; j < 8; ++j) {
    float v = w2[(n * 32 + cb + j) * 9 + tap];
    _Float16 h = (_Float16)v;
    out[j] = (part == 0) ? h : (_Float16)((v - (float)h) * 4096.f);
  }
  *(half8*)((char*)frags + ((size_t)blk * 64 + lane) * 16) = out;
}

// ---------------------------------------------------------------------------
// Kernel 0b: decoder deconv1 B-fragments (single f16).
// ---------------------------------------------------------------------------
__global__ __launch_bounds__(64) void prep_dec1(
    const float* __restrict__ w1, float* __restrict__ frags) {
  const int blk = blockIdx.x;
  const int phase = blk >> 4, ks = blk & 15;
  const int pa = phase >> 1, pb = phase & 1;
  const int st = ks >> 2, kk = ks & 3;
  const int s = st >> 1, tt = st & 1;
  const int lane = threadIdx.x;
  const int kg = lane >> 5, n = lane & 31;
  const int tap = (pa + 2 * s) * 4 + (pb + 2 * tt);
  half8 o;
#pragma unroll
  for (int j = 0; j < 8; ++j) {
    int c = kk * 16 + kg * 8 + j;
    o[j] = (_Float16)w1[tap * 2048 + c * 32 + n];
  }
  *(half8*)((char*)frags + ((size_t)blk * 64 + lane) * 16) = o;
}

// ---------------------------------------------------------------------------
// Kernel 0c: decfc B-fragments (f16). B[k][n] = dfcw[colorig][k], GEMM col
// j = nt*32+n -> (px = j>>6, c = j&63), colorig = c*49+px.
// ---------------------------------------------------------------------------
__global__ __launch_bounds__(64) void prep_dfc(
    const float* __restrict__ dfcw, float* __restrict__ frags) {
  const int blk = blockIdx.x;  // 784 = 98 nt x 8 ks
  const int nt = blk >> 3, ks = blk & 7;
  const int lane = threadIdx.x;
  const int n = lane & 31, kg = lane >> 5;
  const int j = nt * 32 + n;
  const int px = j >> 6, c = j & 63;
  half8 o;
#pragma unroll
  for (int u = 0; u < 8; ++u)
    o[u] = (_Float16)dfcw[(size_t)(c * 49 + px) * 128 + ks * 16 + kg * 8 + u];
  *(half8*)((char*)frags + ((size_t)blk * 64 + lane) * 16) = o;
}

// ---------------------------------------------------------------------------
// Kernel 1: memory row inverse norms
// ---------------------------------------------------------------------------
__global__ __launch_bounds__(256) void norm_kernel(
    const float* __restrict__ memg, float* __restrict__ invn) {
  const int wv = threadIdx.x >> 6, lane = threadIdx.x & 63;
  const int row = blockIdx.x * 4 + wv;
  const float* r = memg + (size_t)row * 128;
  float a = r[lane], b = r[lane + 64];
  float s = wave_reduce_sum(a * a + b * b);
  if (lane == 0) invn[row] = 1.f / fmaxf(sqrtf(s), 1e-12f);
}

// ---------------------------------------------------------------------------
// Kernel 2: MFMA encoder (r6/r8 version — proven 317 us).
// ---------------------------------------------------------------------------
template <int S, bool CENTER>
__device__ __forceinline__ void encoder_body(
    char* smem, const float* __restrict__ x, const float* __restrict__ w1,
    const float* __restrict__ b1, const float* __restrict__ b2,
    const float* __restrict__ fcw, const float* __restrict__ fcb,
    const float* __restrict__ bfrag, float* __restrict__ zout, int zoff,
    int b) {
  constexpr int SP = S + 2;
  constexpr int NBANDS = (S == 28) ? 3 : 2;
  constexpr int RMAX = 12;
  constexpr int NPIX = RMAX * SP;
  constexpr int GSTB = NPIX * 16;
  constexpr int PSTB = 4 * GSTB;

  char* h1s = smem;
  float* xs = (float*)(smem + 2 * PSTB);
  float* w1s = xs + SP * SP;
  float(*featp)[64] = (float(*)[64])(w1s + 288);

  const int t = threadIdx.x;
  const int lane = t & 63;
  const int wv = t >> 6;

  for (int e = t; e < SP * SP; e += TPB) xs[e] = 0.f;
  for (int e = t; e < 288; e += TPB) w1s[e] = w1[e];
  __syncthreads();
  const float* xb = x + (size_t)b * 784 + (CENTER ? (7 * 28 + 7) : 0);
  for (int e = t; e < S * S; e += TPB) {
    int i = e / S, j = e - i * S;
    xs[(i + 1) * SP + (j + 1)] = xb[i * 28 + j];
  }

  float sp0 = 0.f, sp1 = 0.f;
  const float bias0 = b2[lane & 31];
  const float bias1 = b2[32 + (lane & 31)];
  const int gOff = (lane >> 5) * GSTB;
  const char* bgbase = (const char*)bfrag + lane * 16;

#pragma unroll
  for (int band = 0; band < NBANDS; ++band) {
    const int BH_ = (S == 28) ? ((band < 2) ? 10 : 8) : ((band == 0) ? 10 : 4);
    const int b0 = band * 10;
    const int LIMIT = BH_ * S;
    const int MTB = (LIMIT + 31) / 32;
    const int NBLK2 = (MTB + 1) / 2;

    __syncthreads();
    for (int e = t; e < 4 * NPIX; e += TPB) {
      int g = e / NPIX;
      int pix = e - g * NPIX;
      int lr = pix / SP;
      int cw = pix - lr * SP;
      int gr = b0 - 1 + lr;
      int ebase = g * GSTB + pix * 16;
      half8 hi8 = {}, lo8 = {};
      if (gr >= 0 && gr < S && cw >= 1 && cw <= S) {
        float xv[9];
#pragma unroll
        for (int di = 0; di < 3; ++di)
#pragma unroll
          for (int dj = 0; dj < 3; ++dj)
            xv[di * 3 + dj] = xs[(gr + di) * SP + (cw - 1 + dj)];
#pragma unroll
        for (int u = 0; u < 8; ++u) {
          int ch = g * 8 + u;
          float a = b1[ch];
#pragma unroll
          for (int v = 0; v < 9; ++v) a += xv[v] * w1s[ch * 9 + v];
          a = fmaxf(a, 0.f);
          _Float16 h = (_Float16)a;
          hi8[u] = h;
          lo8[u] = (_Float16)((a - (float)h) * 4096.f);
        }
      }
      *(half8*)(h1s + ebase) = hi8;
      *(half8*)(h1s + PSTB + ebase) = lo8;
    }
    __syncthreads();
    for (int mblk = wv; mblk < NBLK2; mblk += 4) {
      const int Mt0 = mblk * 2;
      floatx16 acc[2][2][2] = {};
      int pixB[2];
#pragma unroll
      for (int im = 0; im < 2; ++im) {
        int px = (Mt0 + im) * 32 + (lane & 31);
        px = px < LIMIT ? px : LIMIT - 1;
        int r = px / S;
        int cc = px - r * S;
        pixB[im] = (r * SP + cc) * 16;
      }
#pragma unroll 3
      for (int tap = 0; tap < 9; ++tap) {
        const int di = tap / 3, dj = tap - di * 3;
        const int offT = (di * SP + dj) * 16;
#pragma unroll
        for (int half = 0; half < 2; ++half) {
          const int ks = tap * 2 + half;
          const char* bp = bgbase + ks * 4096;
          const int offA = offT + gOff + half * (2 * GSTB);
          half8 ah0 = *(const half8*)(h1s + pixB[0] + offA);
          half8 al0 = *(const half8*)(h1s + PSTB + pixB[0] + offA);
          half8 ah1 = *(const half8*)(h1s + pixB[1] + offA);
          half8 al1 = *(const half8*)(h1s + PSTB + pixB[1] + offA);
          {  // nt = 0
            half8 bh = *(const half8*)(bp);
            half8 bl = *(const half8*)(bp + 2048);
            acc[0][0][0] = __builtin_amdgcn_mfma_f32_32x32x16_f16(
                ah0, bh, acc[0][0][0], 0, 0, 0);
            acc[0][0][1] = __builtin_amdgcn_mfma_f32_32x32x16_f16(
                ah0, bl, acc[0][0][1], 0, 0, 0);
            acc[0][0][1] = __builtin_amdgcn_mfma_f32_32x32x16_f16(
                al0, bh, acc[0][0][1], 0, 0, 0);
            acc[1][0][0] = __builtin_amdgcn_mfma_f32_32x32x16_f16(
                ah1, bh, acc[1][0][0], 0, 0, 0);
            acc[1][0][1] = __builtin_amdgcn_mfma_f32_32x32x16_f16(
                ah1, bl, acc[1][0][1], 0, 0, 0);
            acc[1][0][1] = __builtin_amdgcn_mfma_f32_32x32x16_f16(
                al1, bh, acc[1][0][1], 0, 0, 0);
          }
          {  // nt = 1
            half8 bh = *(const half8*)(bp + 1024);
            half8 bl = *(const half8*)(bp + 3072);
            acc[0][1][0] = __builtin_amdgcn_mfma_f32_32x32x16_f16(
                ah0, bh, acc[0][1][0], 0, 0, 0);
            acc[0][1][1] = __builtin_amdgcn_mfma_f32_32x32x16_f16(
                ah0, bl, acc[0][1][1], 0, 0, 0);
            acc[0][1][1] = __builtin_amdgcn_mfma_f32_32x32x16_f16(
                al0, bh, acc[0][1][1], 0, 0, 0);
            acc[1][1][0] = __builtin_amdgcn_mfma_f32_32x32x16_f16(
                ah1, bh, acc[1][1][0], 0, 0, 0);
            acc[1][1][1] = __builtin_amdgcn_mfma_f32_32x32x16_f16(
                ah1, bl, acc[1][1][1], 0, 0, 0);
            acc[1][1][1] = __builtin_amdgcn_mfma_f32_32x32x16_f16(
                al1, bh, acc[1][1][1], 0, 0, 0);
          }
        }
      }
#pragma unroll
      for (int im = 0; im < 2; ++im)
#pragma unroll
        for (int reg = 0; reg < 16; ++reg) {
          int row = (reg & 3) + 8 * (reg >> 2) + 4 * (lane >> 5);
          int p = (Mt0 + im) * 32 + row;
          if (p < LIMIT) {
            float v0 =
                acc[im][0][0][reg] + acc[im][0][1][reg] * (1.f / 4096.f) + bias0;
            float v1 =
                acc[im][1][0][reg] + acc[im][1][1][reg] * (1.f / 4096.f) + bias1;
            sp0 += fmaxf(v0, 0.f);
            sp1 += fmaxf(v1, 0.f);
          }
        }
    }
  }
  sp0 += __shfl_xor(sp0, 32);
  sp1 += __shfl_xor(sp1, 32);
  if (lane < 32) {
    featp[wv][lane] = sp0;
    featp[wv][32 + lane] = sp1;
  }
  __syncthreads();
  if (t < 64)
    featp[0][t] = (featp[0][t] + featp[1][t] + featp[2][t] + featp[3][t]) *
                  (1.f / (S * S));
  __syncthreads();
  if (t < 64) {
    float s = 0.f;
#pragma unroll
    for (int i = 0; i < 64; ++i) s += featp[0][i] * fcw[t * 64 + i];
    zout[(size_t)b * 128 + zoff + t] = s + fcb[t];
  }
}

__global__ __launch_bounds__(256, 3) void encoders_fused(
    const float* __restrict__ x, const float* __restrict__ ce_w1,
    const float* __restrict__ ce_b1, const float* __restrict__ ce_b2,
    const float* __restrict__ ce_fcw, const float* __restrict__ ce_fcb,
    const float* __restrict__ ge_w1, const float* __restrict__ ge_b1,
    const float* __restrict__ ge_b2, const float* __restrict__ ge_fcw,
    const float* __restrict__ ge_fcb, const float* __restrict__ frags,
    float* __restrict__ z) {
  __shared__ __align__(16) char smem[51856];
  if (blockIdx.x < 2048)
    encoder_body<28, false>(smem, x, ge_w1, ge_b1, ge_b2, ge_fcw, ge_fcb,
                            frags + 18432, z, 64, blockIdx.x);
  else
    encoder_body<14, true>(smem, x, ce_w1, ce_b1, ce_b2, ce_fcw, ce_fcb, frags,
                           z, 0, blockIdx.x - 2048);
}

// ---------------------------------------------------------------------------
// Kernel 3a: partial match. Grid (256 z-groups, 4 mem-quarters).
// ---------------------------------------------------------------------------
__global__ __launch_bounds__(256) void match_part(
    const float* __restrict__ z, const float* __restrict__ memg,
    const float* __restrict__ invn, float* __restrict__ topvw,
    int* __restrict__ topiw) {
  __shared__ __align__(16) float zs[8][128];
  __shared__ float qv[8][512];
  __shared__ int qi[8][512];
  __shared__ int qn[8];
  __shared__ float rowmin[8];

  const int t = threadIdx.x;
  const int rowbase = blockIdx.x * 8;
  const int mbase = blockIdx.y * 2048;

  for (int e = t; e < 8 * 128; e += TPB) {
    int r = e >> 7, j = e & 127;
    zs[r][j] = z[(size_t)(rowbase + r) * 128 + j];
  }
  if (t < 8) { qn[t] = 0; rowmin[t] = -FLT_MAX; }
  __syncthreads();
  {
    int wv = t >> 6, lane = t & 63;
#pragma unroll
    for (int h = 0; h < 2; ++h) {
      int r = wv + h * 4;
      float a = zs[r][lane], b = zs[r][lane + 64];
      float s = wave_reduce_sum(a * a + b * b);
      float inv = 1.f / fmaxf(sqrtf(s), 1e-12f);
      zs[r][lane] = a * inv;
      zs[r][lane + 64] = b * inv;
    }
  }
  __syncthreads();

  float av[10];
  int ai[10];
#pragma unroll
  for (int i = 0; i < 10; ++i) { av[i] = -FLT_MAX; ai[i] = 0; }

  for (int mt = 0; mt < 4; ++mt) {
    int m0 = mbase + mt * 512 + t;
    float acc0[8] = {}, acc1[8] = {};
    const float4* mr0 = (const float4*)(memg + (size_t)m0 * 128);
    const float4* mr1 = (const float4*)(memg + (size_t)(m0 + 256) * 128);
#pragma unroll 4
    for (int jq = 0; jq < 32; ++jq) {
      float4 a0 = mr0[jq], a1 = mr1[jq];
#pragma unroll
      for (int r = 0; r < 8; ++r) {
        float4 zv = ((const float4*)zs[r])[jq];
        acc0[r] += a0.x * zv.x + a0.y * zv.y + a0.z * zv.z + a0.w * zv.w;
        acc1[r] += a1.x * zv.x + a1.y * zv.y + a1.z * zv.z + a1.w * zv.w;
      }
    }
    float i0 = invn[m0], i1 = invn[m0 + 256];
#pragma unroll
    for (int r = 0; r < 8; ++r) {
      float rm = rowmin[r];
      float v0 = acc0[r] * i0;
      if (v0 > rm) {
        int k = atomicAdd(&qn[r], 1);
        qv[r][k] = v0; qi[r][k] = m0;
      }
      float v1 = acc1[r] * i1;
      if (v1 > rm) {
        int k = atomicAdd(&qn[r], 1);
        qv[r][k] = v1; qi[r][k] = m0 + 256;
      }
    }
    __syncthreads();
    if (t < 8) {
      int n = qn[t];
      for (int k = 0; k < n; ++k) {
        float v = qv[t][k];
        int m = qi[t][k];
        if (v > av[9]) {
#pragma unroll
          for (int i = 0; i < 10; ++i) {
            if (v > av[i]) {
              float tv = av[i]; av[i] = v; v = tv;
              int ti = ai[i]; ai[i] = m; m = ti;
            }
          }
        }
      }
      qn[t] = 0;
      rowmin[t] = av[9];
    }
    __syncthreads();
  }

  if (t < 8) {
    const size_t base = (size_t)(rowbase + t) * 40 + blockIdx.y * 10;
#pragma unroll
    for (int k = 0; k < 10; ++k) {
      topvw[base + k] = av[k];
      topiw[base + k] = ai[k];
    }
  }
}

// ---------------------------------------------------------------------------
// Kernel 3b: merge -> exact top-10 -> softmax -> blend -> zmatch (f16).
// ---------------------------------------------------------------------------
__global__ __launch_bounds__(256) void match_merge(
    const float* __restrict__ topvw, const int* __restrict__ topiw,
    const float* __restrict__ memg, _Float16* __restrict__ zmf16) {
  __shared__ float topw[8][10];
  __shared__ int topidx[8][10];
  const int t = threadIdx.x;
  const int rowbase = blockIdx.x * 8;

  if (t < 8) {
    float av[10];
    int ai[10];
#pragma unroll
    for (int i = 0; i < 10; ++i) { av[i] = -FLT_MAX; ai[i] = 0; }
    const size_t base = (size_t)(rowbase + t) * 40;
    for (int c = 0; c < 40; ++c) {
      float v = topvw[base + c];
      int m = topiw[base + c];
      if (v > av[9]) {
#pragma unroll
        for (int i = 0; i < 10; ++i) {
          if (v > av[i]) {
            float tv = av[i]; av[i] = v; v = tv;
            int ti = ai[i]; ai[i] = m; m = ti;
          }
        }
      }
    }
    float e_[10], s = 0.f;
#pragma unroll
    for (int k = 0; k < 10; ++k) { e_[k] = expf(av[k]); s += e_[k]; }
    float inv = 1.f / s;
#pragma unroll
    for (int k = 0; k < 10; ++k) { topw[t][k] = e_[k] * inv; topidx[t][k] = ai[k]; }
  }
  __syncthreads();
  for (int e = t; e < 8 * 128; e += TPB) {
    int r = e >> 7, d = e & 127;
    float o = 0.f;
#pragma unroll
    for (int k = 0; k < 10; ++k)
      o += topw[r][k] * memg[(size_t)topidx[r][k] * 128 + d];
    zmf16[(size_t)(rowbase + r) * 128 + d] = (_Float16)o;
  }
}

// ---------------------------------------------------------------------------
// Kernel 4: decoder FC via f16 MFMA. Grid (64 M-blocks of 32 rows, 2 N-halves
// of 49 n-tiles). A (zmatch f16) held in registers; B streamed from ws frags.
// Output d0 as f16 in [b][px][c] channel-last order (decoder-native).
// ---------------------------------------------------------------------------
__global__ __launch_bounds__(256) void decfc_kernel(
    const _Float16* __restrict__ zmf16, const float* __restrict__ fcb,
    const float* __restrict__ dfcfrags, _Float16* __restrict__ d0f16) {
  const int t = threadIdx.x;
  const int lane = t & 63;
  const int wv = t >> 6;
  const int r0 = blockIdx.x * 32;
  const int ntbase = blockIdx.y * 49;

  half8 a[8];
  {
    const _Float16* ap =
        zmf16 + (size_t)(r0 + (lane & 31)) * 128 + (lane >> 5) * 8;
#pragma unroll
    for (int ks = 0; ks < 8; ++ks) a[ks] = *(const half8*)(ap + ks * 16);
  }
  const char* fb = (const char*)dfcfrags + lane * 16;

  for (int nt = ntbase + wv; nt < ntbase + 49; nt += 4) {
    half8 bfr[8];
    const char* p = fb + (size_t)nt * 8192;
#pragma unroll
    for (int ks = 0; ks < 8; ++ks) bfr[ks] = *(const half8*)(p + ks * 1024);
    floatx16 acc = {};
#pragma unroll
    for (int ks = 0; ks < 8; ++ks)
      acc = __builtin_amdgcn_mfma_f32_32x32x16_f16(a[ks], bfr[ks], acc, 0, 0, 0);
    const int col = nt * 32 + (lane & 31);
    const int px = col >> 6, c = col & 63;
    const float bias = fcb[c * 49 + px];
#pragma unroll
    for (int reg = 0; reg < 16; ++reg) {
      int row = (reg & 3) + 8 * (reg >> 2) + 4 * (lane >> 5);
      d0f16[((size_t)(r0 + row) * 49 + px) * 64 + c] = (_Float16)(acc[reg] + bias);
    }
  }
}

// ---------------------------------------------------------------------------
// Kernel 5: decoder v4 — deconv1 AND conv2 via f16 MFMA.
// LDS overlay (41408 B):
//   [0,12608):     d0f stage (10368 B) -> d2 fp32 [16][197]
//   [12608,28992): d1f f16 [4 grp][16x16 pix][16 B]
//   [28992,38208): w2s conv2 B-frags [9][64][16 B]
//   d3 fp32 [8][900] = [12608, 41408) overlays d1f+w2s after conv2.
// ---------------------------------------------------------------------------
__global__ __launch_bounds__(256) void decoder_kernel(
    const _Float16* __restrict__ d0f16, const float* __restrict__ b1,
    const float* __restrict__ w2, const float* __restrict__ b2,
    const float* __restrict__ w3, const float* __restrict__ b3,
    const float* __restrict__ w4, const float* __restrict__ b4,
    const float* __restrict__ dec1frags, float* __restrict__ out) {
  __shared__ __align__(16) char dsm[41408];
  char* d0f = dsm;
  float* d2 = (float*)dsm;
  char* d1f = dsm + 12608;
  char* w2s = dsm + 28992;
  float* d3 = (float*)(dsm + 12608);

  const int b = blockIdx.x;
  const int t = threadIdx.x;
  const int lane = t & 63;
  const int wv = t >> 6;

  // ---- phase 1: stage d0f, build w2s, zero d1f
  for (int e = t; e < 648; e += TPB) {
    int g = e / 81, pix = e - g * 81;
    int ih = pix / 9 - 1, iw = pix % 9 - 1;
    half8 hv = {};
    if (ih >= 0 && ih < 7 && iw >= 0 && iw < 7)
      hv = *(const half8*)(d0f16 + ((size_t)b * 49 + ih * 7 + iw) * 64 + g * 8);
    *(half8*)(d0f + e * 16) = hv;
  }
  for (int e = t; e < 576; e += TPB) {
    int tau = e / 64, l = e - tau * 64;
    int n = l & 15, kq = l >> 4;
    half8 v;
#pragma unroll
    for (int u = 0; u < 8; ++u)
      v[u] = (_Float16)w2[(n * 32 + kq * 8 + u) * 9 + tau];
    *(half8*)(w2s + e * 16) = v;
  }
  for (int e = t; e < 1024; e += TPB)
    *(float4*)(d1f + e * 16) = make_float4(0.f, 0.f, 0.f, 0.f);
  __syncthreads();

  // ---- phase 2: deconv1 MFMA (wave = phase), out -> d1f f16 channel-last
  {
    const int pa = wv >> 1, pb = wv & 1;
    const int kg = lane >> 5, o = lane & 31;
    const char* bg = (const char*)dec1frags + wv * 16384 + lane * 16;
    int pxa[2][4];
#pragma unroll
    for (int im = 0; im < 2; ++im) {
      int px = im * 32 + o;
      px = px < 49 ? px : 48;
      int i = px / 7, j2 = px - i * 7;
#pragma unroll
      for (int st = 0; st < 4; ++st) {
        int s = st >> 1, tt = st & 1;
        pxa[im][st] = ((i + pa + s) * 9 + (j2 + pb + tt)) * 16;
      }
    }
    floatx16 acc0 = {}, acc1 = {};
    half8 nb = *(const half8*)(bg);
#pragma unroll
    for (int ks = 0; ks < 16; ++ks) {
      half8 bf = nb;
      if (ks < 15) nb = *(const half8*)(bg + (ks + 1) * 1024);
      const int gbase = (((ks & 3) * 2 + kg) * 81) * 16;
      half8 a0 = *(const half8*)(d0f + gbase + pxa[0][ks >> 2]);
      half8 a1 = *(const half8*)(d0f + gbase + pxa[1][ks >> 2]);
      acc0 = __builtin_amdgcn_mfma_f32_32x32x16_f16(a0, bf, acc0, 0, 0, 0);
      acc1 = __builtin_amdgcn_mfma_f32_32x32x16_f16(a1, bf, acc1, 0, 0, 0);
    }
    const float bias = b1[o];
    char* dst = d1f + (o >> 3) * 4096 + (o & 7) * 2;
#pragma unroll
    for (int im = 0; im < 2; ++im) {
      const floatx16& ac = im ? acc1 : acc0;
#pragma unroll
      for (int reg = 0; reg < 16; ++reg) {
        int row = (reg & 3) + 8 * (reg >> 2) + 4 * kg;
        int px = im * 32 + row;
        if (px < 49) {
          int i = px / 7, j2 = px - i * 7;
          int p = 2 * i + pa, q = 2 * j2 + pb;
          *(_Float16*)(dst + ((p + 1) * 16 + (q + 1)) * 16) =
              (_Float16)fmaxf(ac[reg] + bias, 0.f);
        }
      }
    }
  }
  __syncthreads();

  // ---- phase 3: conv2 via 16x16x32 MFMA. M=196 (13 tiles), N=16, K=288.
  {
    const int m = lane & 15, kq = lane >> 4;
    half8 bq[9];
#pragma unroll
    for (int tau = 0; tau < 9; ++tau)
      bq[tau] = *(const half8*)(w2s + (tau * 64 + lane) * 16);
    for (int mt = wv; mt < 13; mt += 4) {
      int px = mt * 16 + m;
      px = px < 196 ? px : 195;
      const int p = px / 14, q = px - (px / 14) * 14;
      floatx4 acc = {};
#pragma unroll
      for (int tau = 0; tau < 9; ++tau) {
        const int dp = tau / 3, dq = tau - dp * 3;
        half8 av =
            *(const half8*)(d1f + (kq * 256 + (p + dp) * 16 + (q + dq)) * 16);
        acc = __builtin_amdgcn_mfma_f32_16x16x32_f16(av, bq[tau], acc, 0, 0, 0);
      }
      const int o = lane & 15;
      const float bias = b2[o];
#pragma unroll
      for (int reg = 0; reg < 4; ++reg) {
        int row = (lane >> 4) * 4 + reg;
        int opx = mt * 16 + row;
        if (opx < 196) d2[o * 197 + opx] = fmaxf(acc[reg] + bias, 0.f);
      }
    }
  }
  __syncthreads();
  for (int e = t; e < 7200; e += TPB) d3[e] = 0.f;
  __syncthreads();

  // ---- phase 4: deconv2 fp32 (wave = phase)
  {
    const int ph = __builtin_amdgcn_readfirstlane(t >> 6);
    const int pa = ph >> 1, pb = ph & 1;
    const int tb = pa * 4 + pb;
    const float* wA = w3 + (size_t)tb * 128;
    const float* wB = w3 + (size_t)(tb + 2) * 128;
    const float* wC = w3 + (size_t)(tb + 8) * 128;
    const float* wD = w3 + (size_t)(tb + 10) * 128;
#pragma unroll 1
    for (int k = 0; k < 4; ++k) {
      const int px = lane + 64 * k;
      const int cpx = px < 196 ? px : 195;
      const int i = cpx / 14, j = cpx % 14;
      int ih[2], iw[2];
      float mh[2], mw[2];
#pragma unroll
      for (int s = 0; s < 2; ++s) {
        int v = i + pa + s - 1;
        mh[s] = (v >= 0 && v <= 13) ? 1.f : 0.f;
        ih[s] = v < 0 ? 0 : (v > 13 ? 13 : v);
        int u = j + pb + s - 1;
        mw[s] = (u >= 0 && u <= 13) ? 1.f : 0.f;
        iw[s] = u < 0 ? 0 : (u > 13 ? 13 : u);
      }
      const float m00 = mh[0] * mw[0], m01 = mh[0] * mw[1];
      const float m10 = mh[1] * mw[0], m11 = mh[1] * mw[1];
      float acc[8];
#pragma unroll
      for (int oo = 0; oo < 8; ++oo) acc[oo] = b3[oo];
#pragma unroll 2
      for (int c = 0; c < 16; ++c) {
        const float a00 = d2[c * 197 + ih[0] * 14 + iw[0]] * m00;
        const float a01 = d2[c * 197 + ih[0] * 14 + iw[1]] * m01;
        const float a10 = d2[c * 197 + ih[1] * 14 + iw[0]] * m10;
        const float a11 = d2[c * 197 + ih[1] * 14 + iw[1]] * m11;
        const int wb = c * 8;
#pragma unroll
        for (int oo = 0; oo < 8; ++oo)
          acc[oo] += a00 * wA[wb + oo] + a01 * wB[wb + oo] +
                     a10 * wC[wb + oo] + a11 * wD[wb + oo];
      }
      if (px < 196) {
        const int p = 2 * i + pa, q = 2 * j + pb;
        const int widx = (p + 1) * 30 + (q + 1);
#pragma unroll
        for (int oo = 0; oo < 8; ++oo)
          d3[oo * 900 + widx] = fmaxf(acc[oo], 0.f);
      }
    }
  }
  __syncthreads();

  // ---- phase 5: final conv
  for (int e = t; e < 784; e += TPB) {
    int p = e / 28, q = e - p * 28;
    float a = b4[0];
#pragma unroll
    for (int c = 0; c < 8; ++c) {
      const float* bp = &d3[c * 900 + p * 30 + q];
#pragma unroll
      for (int di = 0; di < 3; ++di)
#pragma unroll
        for (int dj = 0; dj < 3; ++dj)
          a += bp[di * 30 + dj] * w4[c * 9 + di * 3 + dj];
    }
    out[(size_t)b * 784 + e] = a;
  }
}

// ---------------------------------------------------------------------------
extern "C" void kernel_launch(void* const* d_in, const int* in_sizes, int n_in,
                              void* d_out, int out_size, void* d_ws,
                              size_t ws_size, hipStream_t stream) {
  const float* x      = (const float*)d_in[0];
  const float* ce_w1  = (const float*)d_in[1];
  const float* ce_b1  = (const float*)d_in[2];
  const float* ce_w2  = (const float*)d_in[3];
  const float* ce_b2  = (const float*)d_in[4];
  const float* ce_fcw = (const float*)d_in[5];
  const float* ce_fcb = (const float*)d_in[6];
  const float* ge_w1  = (const float*)d_in[7];
  const float* ge_b1  = (const float*)d_in[8];
  const float* ge_w2  = (const float*)d_in[9];
  const float* ge_b2  = (const float*)d_in[10];
  const float* ge_fcw = (const float*)d_in[11];
  const float* ge_fcb = (const float*)d_in[12];
  const float* memg   = (const float*)d_in[13];
  const float* dfcw   = (const float*)d_in[14];
  const float* dfcb   = (const float*)d_in[15];
  const float* d_w1   = (const float*)d_in[16];
  const float* d_b1   = (const float*)d_in[17];
  const float* d_w2   = (const float*)d_in[18];
  const float* d_b2   = (const float*)d_in[19];
  const float* d_w3   = (const float*)d_in[20];
  const float* d_b3   = (const float*)d_in[21];
  const float* d_w4   = (const float*)d_in[22];
  const float* d_b4   = (const float*)d_in[23];
  float* outp = (float*)d_out;

  // ws layout (float offsets): z[262144] | zmf16 slot[131072] | invn[8192] |
  // enc frags[36864] | dec1frags[16384] | dfcfrags[200704] | tail region
  // (topv/topi then d0f16 — sequential lifetimes).
  float*     ws        = (float*)d_ws;
  float*     z         = ws;
  _Float16*  zmf16     = (_Float16*)(ws + 262144);
  float*     invn      = ws + 262144 + 131072;
  float*     frags     = invn + 8192;
  float*     dec1frags = frags + 36864;
  float*     dfcfrags  = dec1frags + 16384;
  float*     tailbase  = dfcfrags + 200704;
  float*     topvw     = tailbase;
  int*       topiw     = (int*)(tailbase + 81920);
  _Float16*  d0f16     = (_Float16*)tailbase;

  prep_bfrags<<<144, 64, 0, stream>>>(ce_w2, ge_w2, frags);
  prep_dec1<<<64, 64, 0, stream>>>(d_w1, dec1frags);
  prep_dfc<<<784, 64, 0, stream>>>(dfcw, dfcfrags);
  norm_kernel<<<2048, TPB, 0, stream>>>(memg, invn);
  encoders_fused<<<4096, TPB, 0, stream>>>(x, ce_w1, ce_b1, ce_b2, ce_fcw,
                                           ce_fcb, ge_w1, ge_b1, ge_b2, ge_fcw,
                                           ge_fcb, frags, z);
  match_part<<<dim3(256, 4), TPB, 0, stream>>>(z, memg, invn, topvw, topiw);
  match_merge<<<256, TPB, 0, stream>>>(topvw, topiw, memg, zmf16);
  decfc_kernel<<<dim3(64, 2), TPB, 0, stream>>>(zmf16, dfcb, dfcfrags, d0f16);
  decoder_kernel<<<2048, TPB, 0, stream>>>(d0f16, d_b1, d_w2, d_b2, d_w3, d_b3,
                                           d_w4, d_b4, dec1frags, outp);
}

// Round 10
// 681.944 us; speedup vs baseline: 1.6064x; 1.0437x over previous
//
#include <hip/hip_runtime.h>
#include <cfloat>
#include <cmath>

#define TPB 256

typedef _Float16 half8 __attribute__((ext_vector_type(8)));
typedef float floatx16 __attribute__((ext_vector_type(16)));
typedef float floatx4 __attribute__((ext_vector_type(4)));

__device__ __forceinline__ float wave_reduce_sum(float v) {
#pragma unroll
  for (int off = 32; off > 0; off >>= 1) v += __shfl_xor(v, off, 64);
  return v;
}

// ---------------------------------------------------------------------------
// Kernel 0a: encoder conv2 B-fragments (2-part f16 split).
// ---------------------------------------------------------------------------
__global__ __launch_bounds__(64) void prep_bfrags(
    const float* __restrict__ ce_w2, const float* __restrict__ ge_w2,
    float* __restrict__ frags) {
  const int blk = blockIdx.x;  // 144 = 2 enc x 72 frags
  const int enc = blk / 72;
  const int frag = blk % 72;
  const int ks = frag >> 2, part = (frag >> 1) & 1, nt = frag & 1;
  const int tap = ks >> 1, half = ks & 1;
  const int lane = threadIdx.x;
  const float* w2 = enc ? ge_w2 : ce_w2;
  const int n = nt * 32 + (lane & 31);
  const int cb = half * 16 + (lane >> 5) * 8;
  half8 out;
#pragma unroll
  for (int j = 0; j < 8; ++j) {
    float v = w2[(n * 32 + cb + j) * 9 + tap];
    _Float16 h = (_Float16)v;
    out[j] = (part == 0) ? h : (_Float16)((v - (float)h) * 4096.f);
  }
  *(half8*)((char*)frags + ((size_t)blk * 64 + lane) * 16) = out;
}

// ---------------------------------------------------------------------------
// Kernel 0b: decoder deconv1 B-fragments (single f16).
// ---------------------------------------------------------------------------
__global__ __launch_bounds__(64) void prep_dec1(
    const float* __restrict__ w1, float* __restrict__ frags) {
  const int blk = blockIdx.x;
  const int phase = blk >> 4, ks = blk & 15;
  const int pa = phase >> 1, pb = phase & 1;
  const int st = ks >> 2, kk = ks & 3;
  const int s = st >> 1, tt = st & 1;
  const int lane = threadIdx.x;
  const int kg = lane >> 5, n = lane & 31;
  const int tap = (pa + 2 * s) * 4 + (pb + 2 * tt);
  half8 o;
#pragma unroll
  for (int j = 0; j < 8; ++j) {
    int c = kk * 16 + kg * 8 + j;
    o[j] = (_Float16)w1[tap * 2048 + c * 32 + n];
  }
  *(half8*)((char*)frags + ((size_t)blk * 64 + lane) * 16) = o;
}

// ---------------------------------------------------------------------------
// Kernel 0c: decfc B-fragments (f16).
// ---------------------------------------------------------------------------
__global__ __launch_bounds__(64) void prep_dfc(
    const float* __restrict__ dfcw, float* __restrict__ frags) {
  const int blk = blockIdx.x;  // 784 = 98 nt x 8 ks
  const int nt = blk >> 3, ks = blk & 7;
  const int lane = threadIdx.x;
  const int n = lane & 31, kg = lane >> 5;
  const int j = nt * 32 + n;
  const int px = j >> 6, c = j & 63;
  half8 o;
#pragma unroll
  for (int u = 0; u < 8; ++u)
    o[u] = (_Float16)dfcw[(size_t)(c * 49 + px) * 128 + ks * 16 + kg * 8 + u];
  *(half8*)((char*)frags + ((size_t)blk * 64 + lane) * 16) = o;
}

// ---------------------------------------------------------------------------
// Kernel 0d: mem B-fragments for match (2-part f16 split).
// blk = T*16 + p*8 + ks (T = mem 32-row tile). B[k][n] = mem[T*32+n][ks*16+k].
// ---------------------------------------------------------------------------
__global__ __launch_bounds__(64) void prep_mem(
    const float* __restrict__ memg, float* __restrict__ frags) {
  const int blk = blockIdx.x;  // 4096 = 256 tiles x 16 slots
  const int slot = blk & 15;
  const int p = slot >> 3, ks = slot & 7;
  const int T = blk >> 4;
  const int lane = threadIdx.x;
  const int n = lane & 31, kg = lane >> 5;
  const float* src = memg + (size_t)(T * 32 + n) * 128 + ks * 16 + kg * 8;
  half8 o;
#pragma unroll
  for (int j = 0; j < 8; ++j) {
    float v = src[j];
    _Float16 h = (_Float16)v;
    o[j] = p ? (_Float16)((v - (float)h) * 4096.f) : h;
  }
  *(half8*)((char*)frags + ((size_t)blk * 64 + lane) * 16) = o;
}

// ---------------------------------------------------------------------------
// Kernel 1: memory row inverse norms
// ---------------------------------------------------------------------------
__global__ __launch_bounds__(256) void norm_kernel(
    const float* __restrict__ memg, float* __restrict__ invn) {
  const int wv = threadIdx.x >> 6, lane = threadIdx.x & 63;
  const int row = blockIdx.x * 4 + wv;
  const float* r = memg + (size_t)row * 128;
  float a = r[lane], b = r[lane + 64];
  float s = wave_reduce_sum(a * a + b * b);
  if (lane == 0) invn[row] = 1.f / fmaxf(sqrtf(s), 1e-12f);
}

// ---------------------------------------------------------------------------
// Kernel 2: MFMA encoder (r6/r8 version — proven 317 us).
// ---------------------------------------------------------------------------
template <int S, bool CENTER>
__device__ __forceinline__ void encoder_body(
    char* smem, const float* __restrict__ x, const float* __restrict__ w1,
    const float* __restrict__ b1, const float* __restrict__ b2,
    const float* __restrict__ fcw, const float* __restrict__ fcb,
    const float* __restrict__ bfrag, float* __restrict__ zout, int zoff,
    int b) {
  constexpr int SP = S + 2;
  constexpr int NBANDS = (S == 28) ? 3 : 2;
  constexpr int RMAX = 12;
  constexpr int NPIX = RMAX * SP;
  constexpr int GSTB = NPIX * 16;
  constexpr int PSTB = 4 * GSTB;

  char* h1s = smem;
  float* xs = (float*)(smem + 2 * PSTB);
  float* w1s = xs + SP * SP;
  float(*featp)[64] = (float(*)[64])(w1s + 288);

  const int t = threadIdx.x;
  const int lane = t & 63;
  const int wv = t >> 6;

  for (int e = t; e < SP * SP; e += TPB) xs[e] = 0.f;
  for (int e = t; e < 288; e += TPB) w1s[e] = w1[e];
  __syncthreads();
  const float* xb = x + (size_t)b * 784 + (CENTER ? (7 * 28 + 7) : 0);
  for (int e = t; e < S * S; e += TPB) {
    int i = e / S, j = e - i * S;
    xs[(i + 1) * SP + (j + 1)] = xb[i * 28 + j];
  }

  float sp0 = 0.f, sp1 = 0.f;
  const float bias0 = b2[lane & 31];
  const float bias1 = b2[32 + (lane & 31)];
  const int gOff = (lane >> 5) * GSTB;
  const char* bgbase = (const char*)bfrag + lane * 16;

#pragma unroll
  for (int band = 0; band < NBANDS; ++band) {
    const int BH_ = (S == 28) ? ((band < 2) ? 10 : 8) : ((band == 0) ? 10 : 4);
    const int b0 = band * 10;
    const int LIMIT = BH_ * S;
    const int MTB = (LIMIT + 31) / 32;
    const int NBLK2 = (MTB + 1) / 2;

    __syncthreads();
    for (int e = t; e < 4 * NPIX; e += TPB) {
      int g = e / NPIX;
      int pix = e - g * NPIX;
      int lr = pix / SP;
      int cw = pix - lr * SP;
      int gr = b0 - 1 + lr;
      int ebase = g * GSTB + pix * 16;
      half8 hi8 = {}, lo8 = {};
      if (gr >= 0 && gr < S && cw >= 1 && cw <= S) {
        float xv[9];
#pragma unroll
        for (int di = 0; di < 3; ++di)
#pragma unroll
          for (int dj = 0; dj < 3; ++dj)
            xv[di * 3 + dj] = xs[(gr + di) * SP + (cw - 1 + dj)];
#pragma unroll
        for (int u = 0; u < 8; ++u) {
          int ch = g * 8 + u;
          float a = b1[ch];
#pragma unroll
          for (int v = 0; v < 9; ++v) a += xv[v] * w1s[ch * 9 + v];
          a = fmaxf(a, 0.f);
          _Float16 h = (_Float16)a;
          hi8[u] = h;
          lo8[u] = (_Float16)((a - (float)h) * 4096.f);
        }
      }
      *(half8*)(h1s + ebase) = hi8;
      *(half8*)(h1s + PSTB + ebase) = lo8;
    }
    __syncthreads();
    for (int mblk = wv; mblk < NBLK2; mblk += 4) {
      const int Mt0 = mblk * 2;
      floatx16 acc[2][2][2] = {};
      int pixB[2];
#pragma unroll
      for (int im = 0; im < 2; ++im) {
        int px = (Mt0 + im) * 32 + (lane & 31);
        px = px < LIMIT ? px : LIMIT - 1;
        int r = px / S;
        int cc = px - r * S;
        pixB[im] = (r * SP + cc) * 16;
      }
#pragma unroll 3
      for (int tap = 0; tap < 9; ++tap) {
        const int di = tap / 3, dj = tap - di * 3;
        const int offT = (di * SP + dj) * 16;
#pragma unroll
        for (int half = 0; half < 2; ++half) {
          const int ks = tap * 2 + half;
          const char* bp = bgbase + ks * 4096;
          const int offA = offT + gOff + half * (2 * GSTB);
          half8 ah0 = *(const half8*)(h1s + pixB[0] + offA);
          half8 al0 = *(const half8*)(h1s + PSTB + pixB[0] + offA);
          half8 ah1 = *(const half8*)(h1s + pixB[1] + offA);
          half8 al1 = *(const half8*)(h1s + PSTB + pixB[1] + offA);
          {  // nt = 0
            half8 bh = *(const half8*)(bp);
            half8 bl = *(const half8*)(bp + 2048);
            acc[0][0][0] = __builtin_amdgcn_mfma_f32_32x32x16_f16(
                ah0, bh, acc[0][0][0], 0, 0, 0);
            acc[0][0][1] = __builtin_amdgcn_mfma_f32_32x32x16_f16(
                ah0, bl, acc[0][0][1], 0, 0, 0);
            acc[0][0][1] = __builtin_amdgcn_mfma_f32_32x32x16_f16(
                al0, bh, acc[0][0][1], 0, 0, 0);
            acc[1][0][0] = __builtin_amdgcn_mfma_f32_32x32x16_f16(
                ah1, bh, acc[1][0][0], 0, 0, 0);
            acc[1][0][1] = __builtin_amdgcn_mfma_f32_32x32x16_f16(
                ah1, bl, acc[1][0][1], 0, 0, 0);
            acc[1][0][1] = __builtin_amdgcn_mfma_f32_32x32x16_f16(
                al1, bh, acc[1][0][1], 0, 0, 0);
          }
          {  // nt = 1
            half8 bh = *(const half8*)(bp + 1024);
            half8 bl = *(const half8*)(bp + 3072);
            acc[0][1][0] = __builtin_amdgcn_mfma_f32_32x32x16_f16(
                ah0, bh, acc[0][1][0], 0, 0, 0);
            acc[0][1][1] = __builtin_amdgcn_mfma_f32_32x32x16_f16(
                ah0, bl, acc[0][1][1], 0, 0, 0);
            acc[0][1][1] = __builtin_amdgcn_mfma_f32_32x32x16_f16(
                al0, bh, acc[0][1][1], 0, 0, 0);
            acc[1][1][0] = __builtin_amdgcn_mfma_f32_32x32x16_f16(
                ah1, bh, acc[1][1][0], 0, 0, 0);
            acc[1][1][1] = __builtin_amdgcn_mfma_f32_32x32x16_f16(
                ah1, bl, acc[1][1][1], 0, 0, 0);
            acc[1][1][1] = __builtin_amdgcn_mfma_f32_32x32x16_f16(
                al1, bh, acc[1][1][1], 0, 0, 0);
          }
        }
      }
#pragma unroll
      for (int im = 0; im < 2; ++im)
#pragma unroll
        for (int reg = 0; reg < 16; ++reg) {
          int row = (reg & 3) + 8 * (reg >> 2) + 4 * (lane >> 5);
          int p = (Mt0 + im) * 32 + row;
          if (p < LIMIT) {
            float v0 =
                acc[im][0][0][reg] + acc[im][0][1][reg] * (1.f / 4096.f) + bias0;
            float v1 =
                acc[im][1][0][reg] + acc[im][1][1][reg] * (1.f / 4096.f) + bias1;
            sp0 += fmaxf(v0, 0.f);
            sp1 += fmaxf(v1, 0.f);
          }
        }
    }
  }
  sp0 += __shfl_xor(sp0, 32);
  sp1 += __shfl_xor(sp1, 32);
  if (lane < 32) {
    featp[wv][lane] = sp0;
    featp[wv][32 + lane] = sp1;
  }
  __syncthreads();
  if (t < 64)
    featp[0][t] = (featp[0][t] + featp[1][t] + featp[2][t] + featp[3][t]) *
                  (1.f / (S * S));
  __syncthreads();
  if (t < 64) {
    float s = 0.f;
#pragma unroll
    for (int i = 0; i < 64; ++i) s += featp[0][i] * fcw[t * 64 + i];
    zout[(size_t)b * 128 + zoff + t] = s + fcb[t];
  }
}

__global__ __launch_bounds__(256, 3) void encoders_fused(
    const float* __restrict__ x, const float* __restrict__ ce_w1,
    const float* __restrict__ ce_b1, const float* __restrict__ ce_b2,
    const float* __restrict__ ce_fcw, const float* __restrict__ ce_fcb,
    const float* __restrict__ ge_w1, const float* __restrict__ ge_b1,
    const float* __restrict__ ge_b2, const float* __restrict__ ge_fcw,
    const float* __restrict__ ge_fcb, const float* __restrict__ frags,
    float* __restrict__ z) {
  __shared__ __align__(16) char smem[51856];
  if (blockIdx.x < 2048)
    encoder_body<28, false>(smem, x, ge_w1, ge_b1, ge_b2, ge_fcw, ge_fcb,
                            frags + 18432, z, 64, blockIdx.x);
  else
    encoder_body<14, true>(smem, x, ce_w1, ce_b1, ce_b2, ce_fcw, ce_fcb, frags,
                           z, 0, blockIdx.x - 2048);
}

// ---------------------------------------------------------------------------
// Kernel 3a: match via split-f16 MFMA. Grid (64 z-blocks of 32 rows,
// 16 mem-slices of 512 rows). sim = zn·mem^T via 3-term split MFMA
// (err ~2^-22), exact top-10 per (row, slice) via per-round candidate queue
// (cap 128 = exact per-round value count; no overflow possible).
// LDS: qv[32][128] (16K, overlays zs) | qi (16K) | zfrag (16K) | rowmin/qn.
// ---------------------------------------------------------------------------
__global__ __launch_bounds__(256) void match_mfma(
    const float* __restrict__ z, const float* __restrict__ memfrags,
    const float* __restrict__ invn, float* __restrict__ topvw,
    int* __restrict__ topiw) {
  __shared__ __align__(16) char smem[49408];
  float* zs = (float*)smem;            // [32][128] fp32 (staging)
  float* qv = (float*)smem;            // [32][128] (after zs dead)
  int* qi = (int*)(smem + 16384);      // [32][128]
  char* zfrag = smem + 32768;          // 16 KB: [p][ks][kg*32+m][16B]
  float* rowmin = (float*)(smem + 49152);
  int* qn = (int*)(smem + 49152 + 128);

  const int t = threadIdx.x;
  const int lane = t & 63;
  const int wv = t >> 6;
  const int rowbase = blockIdx.x * 32;
  const int Tbase = blockIdx.y * 16;

  for (int e = t; e < 4096; e += TPB) zs[e] = z[(size_t)rowbase * 128 + e];
  if (t < 32) { rowmin[t] = -FLT_MAX; qn[t] = 0; }
  __syncthreads();
#pragma unroll
  for (int h = 0; h < 8; ++h) {
    int r = wv * 8 + h;
    float a = zs[r * 128 + lane], b = zs[r * 128 + 64 + lane];
    float s = wave_reduce_sum(a * a + b * b);
    float inv = 1.f / fmaxf(sqrtf(s), 1e-12f);
    zs[r * 128 + lane] = a * inv;
    zs[r * 128 + 64 + lane] = b * inv;
  }
  __syncthreads();
  // build z A-fragments (2-part split), frag-major: entry (ks*64+kg*32+m)
  for (int e = t; e < 4096; e += TPB) {
    int m = e >> 7, c = e & 127;
    float v = zs[m * 128 + c];
    _Float16 h = (_Float16)v;
    _Float16 l = (_Float16)((v - (float)h) * 4096.f);
    int ks = c >> 4, kg = (c >> 3) & 1, j = c & 7;
    int off = (ks * 64 + kg * 32 + m) * 16 + j * 2;
    *(_Float16*)(zfrag + off) = h;
    *(_Float16*)(zfrag + 8192 + off) = l;
  }
  __syncthreads();

  // hoist A-fragments to registers (constant across all 16 n-tiles)
  half8 ah[8], al[8];
  {
    const char* zf = zfrag + ((lane >> 5) * 32 + (lane & 31)) * 16;
#pragma unroll
    for (int ks = 0; ks < 8; ++ks) {
      ah[ks] = *(const half8*)(zf + ks * 1024);
      al[ks] = *(const half8*)(zf + 8192 + ks * 1024);
    }
  }

  float av[10];
  int ai[10];
#pragma unroll
  for (int i = 0; i < 10; ++i) { av[i] = -FLT_MAX; ai[i] = 0; }

#pragma unroll 1
  for (int round = 0; round < 4; ++round) {
    const int T = Tbase + round * 4 + wv;
    const char* bf = (const char*)memfrags + (size_t)T * 16384 + lane * 16;
    floatx16 acc0 = {}, acc1 = {};
#pragma unroll
    for (int ks = 0; ks < 8; ++ks) {
      half8 bh = *(const half8*)(bf + ks * 1024);
      half8 bl = *(const half8*)(bf + 8192 + ks * 1024);
      acc0 = __builtin_amdgcn_mfma_f32_32x32x16_f16(ah[ks], bh, acc0, 0, 0, 0);
      acc1 = __builtin_amdgcn_mfma_f32_32x32x16_f16(ah[ks], bl, acc1, 0, 0, 0);
      acc1 = __builtin_amdgcn_mfma_f32_32x32x16_f16(al[ks], bh, acc1, 0, 0, 0);
    }
    const int gn = T * 32 + (lane & 31);
    const float iv = invn[gn];
#pragma unroll
    for (int reg = 0; reg < 16; ++reg) {
      int m = (reg & 3) + 8 * (reg >> 2) + 4 * (lane >> 5);
      float v = (acc0[reg] + acc1[reg] * (1.f / 4096.f)) * iv;
      if (v > rowmin[m]) {
        int k = atomicAdd(&qn[m], 1);
        qv[m * 128 + k] = v;
        qi[m * 128 + k] = gn;
      }
    }
    __syncthreads();
    if (t < 32) {
      int n = qn[t];
      for (int k = 0; k < n; ++k) {
        float v = qv[t * 128 + k];
        int mm = qi[t * 128 + k];
        if (v > av[9]) {
#pragma unroll
          for (int i = 0; i < 10; ++i) {
            if (v > av[i]) {
              float tv = av[i]; av[i] = v; v = tv;
              int ti = ai[i]; ai[i] = mm; mm = ti;
            }
          }
        }
      }
      qn[t] = 0;
      rowmin[t] = av[9];
    }
    __syncthreads();
  }

  if (t < 32) {
    const size_t base = (size_t)(rowbase + t) * 160 + blockIdx.y * 10;
#pragma unroll
    for (int k = 0; k < 10; ++k) {
      topvw[base + k] = av[k];
      topiw[base + k] = ai[k];
    }
  }
}

// ---------------------------------------------------------------------------
// Kernel 3b: merge 16x10 candidates -> exact top-10 -> softmax -> blend (f16).
// ---------------------------------------------------------------------------
__global__ __launch_bounds__(256) void match_merge(
    const float* __restrict__ topvw, const int* __restrict__ topiw,
    const float* __restrict__ memg, _Float16* __restrict__ zmf16) {
  __shared__ float topw[8][10];
  __shared__ int topidx[8][10];
  const int t = threadIdx.x;
  const int rowbase = blockIdx.x * 8;

  if (t < 8) {
    float av[10];
    int ai[10];
#pragma unroll
    for (int i = 0; i < 10; ++i) { av[i] = -FLT_MAX; ai[i] = 0; }
    const size_t base = (size_t)(rowbase + t) * 160;
    for (int c = 0; c < 160; ++c) {
      float v = topvw[base + c];
      int m = topiw[base + c];
      if (v > av[9]) {
#pragma unroll
        for (int i = 0; i < 10; ++i) {
          if (v > av[i]) {
            float tv = av[i]; av[i] = v; v = tv;
            int ti = ai[i]; ai[i] = m; m = ti;
          }
        }
      }
    }
    float e_[10], s = 0.f;
#pragma unroll
    for (int k = 0; k < 10; ++k) { e_[k] = expf(av[k]); s += e_[k]; }
    float inv = 1.f / s;
#pragma unroll
    for (int k = 0; k < 10; ++k) { topw[t][k] = e_[k] * inv; topidx[t][k] = ai[k]; }
  }
  __syncthreads();
  for (int e = t; e < 8 * 128; e += TPB) {
    int r = e >> 7, d = e & 127;
    float o = 0.f;
#pragma unroll
    for (int k = 0; k < 10; ++k)
      o += topw[r][k] * memg[(size_t)topidx[r][k] * 128 + d];
    zmf16[(size_t)(rowbase + r) * 128 + d] = (_Float16)o;
  }
}

// ---------------------------------------------------------------------------
// Kernel 4: decoder FC via f16 MFMA (r9 verified).
// ---------------------------------------------------------------------------
__global__ __launch_bounds__(256) void decfc_kernel(
    const _Float16* __restrict__ zmf16, const float* __restrict__ fcb,
    const float* __restrict__ dfcfrags, _Float16* __restrict__ d0f16) {
  const int t = threadIdx.x;
  const int lane = t & 63;
  const int wv = t >> 6;
  const int r0 = blockIdx.x * 32;
  const int ntbase = blockIdx.y * 49;

  half8 a[8];
  {
    const _Float16* ap =
        zmf16 + (size_t)(r0 + (lane & 31)) * 128 + (lane >> 5) * 8;
#pragma unroll
    for (int ks = 0; ks < 8; ++ks) a[ks] = *(const half8*)(ap + ks * 16);
  }
  const char* fb = (const char*)dfcfrags + lane * 16;

  for (int nt = ntbase + wv; nt < ntbase + 49; nt += 4) {
    half8 bfr[8];
    const char* p = fb + (size_t)nt * 8192;
#pragma unroll
    for (int ks = 0; ks < 8; ++ks) bfr[ks] = *(const half8*)(p + ks * 1024);
    floatx16 acc = {};
#pragma unroll
    for (int ks = 0; ks < 8; ++ks)
      acc = __builtin_amdgcn_mfma_f32_32x32x16_f16(a[ks], bfr[ks], acc, 0, 0, 0);
    const int col = nt * 32 + (lane & 31);
    const int px = col >> 6, c = col & 63;
    const float bias = fcb[c * 49 + px];
#pragma unroll
    for (int reg = 0; reg < 16; ++reg) {
      int row = (reg & 3) + 8 * (reg >> 2) + 4 * (lane >> 5);
      d0f16[((size_t)(r0 + row) * 49 + px) * 64 + c] = (_Float16)(acc[reg] + bias);
    }
  }
}

// ---------------------------------------------------------------------------
// Kernel 5: decoder v4 (r9 verified) — deconv1 + conv2 via f16 MFMA.
// ---------------------------------------------------------------------------
__global__ __launch_bounds__(256) void decoder_kernel(
    const _Float16* __restrict__ d0f16, const float* __restrict__ b1,
    const float* __restrict__ w2, const float* __restrict__ b2,
    const float* __restrict__ w3, const float* __restrict__ b3,
    const float* __restrict__ w4, const float* __restrict__ b4,
    const float* __restrict__ dec1frags, float* __restrict__ out) {
  __shared__ __align__(16) char dsm[41408];
  char* d0f = dsm;
  float* d2 = (float*)dsm;
  char* d1f = dsm + 12608;
  char* w2s = dsm + 28992;
  float* d3 = (float*)(dsm + 12608);

  const int b = blockIdx.x;
  const int t = threadIdx.x;
  const int lane = t & 63;
  const int wv = t >> 6;

  for (int e = t; e < 648; e += TPB) {
    int g = e / 81, pix = e - g * 81;
    int ih = pix / 9 - 1, iw = pix % 9 - 1;
    half8 hv = {};
    if (ih >= 0 && ih < 7 && iw >= 0 && iw < 7)
      hv = *(const half8*)(d0f16 + ((size_t)b * 49 + ih * 7 + iw) * 64 + g * 8);
    *(half8*)(d0f + e * 16) = hv;
  }
  for (int e = t; e < 576; e += TPB) {
    int tau = e / 64, l = e - tau * 64;
    int n = l & 15, kq = l >> 4;
    half8 v;
#pragma unroll
    for (int u = 0; u < 8; ++u)
      v[u] = (_Float16)w2[(n * 32 + kq * 8 + u) * 9 + tau];
    *(half8*)(w2s + e * 16) = v;
  }
  for (int e = t; e < 1024; e += TPB)
    *(float4*)(d1f + e * 16) = make_float4(0.f, 0.f, 0.f, 0.f);
  __syncthreads();

  {
    const int pa = wv >> 1, pb = wv & 1;
    const int kg = lane >> 5, o = lane & 31;
    const char* bg = (const char*)dec1frags + wv * 16384 + lane * 16;
    int pxa[2][4];
#pragma unroll
    for (int im = 0; im < 2; ++im) {
      int px = im * 32 + o;
      px = px < 49 ? px : 48;
      int i = px / 7, j2 = px - i * 7;
#pragma unroll
      for (int st = 0; st < 4; ++st) {
        int s = st >> 1, tt = st & 1;
        pxa[im][st] = ((i + pa + s) * 9 + (j2 + pb + tt)) * 16;
      }
    }
    floatx16 acc0 = {}, acc1 = {};
    half8 nb = *(const half8*)(bg);
#pragma unroll
    for (int ks = 0; ks < 16; ++ks) {
      half8 bf = nb;
      if (ks < 15) nb = *(const half8*)(bg + (ks + 1) * 1024);
      const int gbase = (((ks & 3) * 2 + kg) * 81) * 16;
      half8 a0 = *(const half8*)(d0f + gbase + pxa[0][ks >> 2]);
      half8 a1 = *(const half8*)(d0f + gbase + pxa[1][ks >> 2]);
      acc0 = __builtin_amdgcn_mfma_f32_32x32x16_f16(a0, bf, acc0, 0, 0, 0);
      acc1 = __builtin_amdgcn_mfma_f32_32x32x16_f16(a1, bf, acc1, 0, 0, 0);
    }
    const float bias = b1[o];
    char* dst = d1f + (o >> 3) * 4096 + (o & 7) * 2;
#pragma unroll
    for (int im = 0; im < 2; ++im) {
      const floatx16& ac = im ? acc1 : acc0;
#pragma unroll
      for (int reg = 0; reg < 16; ++reg) {
        int row = (reg & 3) + 8 * (reg >> 2) + 4 * kg;
        int px = im * 32 + row;
        if (px < 49) {
          int i = px / 7, j2 = px - i * 7;
          int p = 2 * i + pa, q = 2 * j2 + pb;
          *(_Float16*)(dst + ((p + 1) * 16 + (q + 1)) * 16) =
              (_Float16)fmaxf(ac[reg] + bias, 0.f);
        }
      }
    }
  }
  __syncthreads();

  {
    const int m = lane & 15, kq = lane >> 4;
    half8 bq[9];
#pragma unroll
    for (int tau = 0; tau < 9; ++tau)
      bq[tau] = *(const half8*)(w2s + (tau * 64 + lane) * 16);
    for (int mt = wv; mt < 13; mt += 4) {
      int px = mt * 16 + m;
      px = px < 196 ? px : 195;
      const int p = px / 14, q = px - (px / 14) * 14;
      floatx4 acc = {};
#pragma unroll
      for (int tau = 0; tau < 9; ++tau) {
        const int dp = tau / 3, dq = tau - dp * 3;
        half8 av =
            *(const half8*)(d1f + (kq * 256 + (p + dp) * 16 + (q + dq)) * 16);
        acc = __builtin_amdgcn_mfma_f32_16x16x32_f16(av, bq[tau], acc, 0, 0, 0);
      }
      const int o = lane & 15;
      const float bias = b2[o];
#pragma unroll
      for (int reg = 0; reg < 4; ++reg) {
        int row = (lane >> 4) * 4 + reg;
        int opx = mt * 16 + row;
        if (opx < 196) d2[o * 197 + opx] = fmaxf(acc[reg] + bias, 0.f);
      }
    }
  }
  __syncthreads();
  for (int e = t; e < 7200; e += TPB) d3[e] = 0.f;
  __syncthreads();

  {
    const int ph = __builtin_amdgcn_readfirstlane(t >> 6);
    const int pa = ph >> 1, pb = ph & 1;
    const int tb = pa * 4 + pb;
    const float* wA = w3 + (size_t)tb * 128;
    const float* wB = w3 + (size_t)(tb + 2) * 128;
    const float* wC = w3 + (size_t)(tb + 8) * 128;
    const float* wD = w3 + (size_t)(tb + 10) * 128;
#pragma unroll 1
    for (int k = 0; k < 4; ++k) {
      const int px = lane + 64 * k;
      const int cpx = px < 196 ? px : 195;
      const int i = cpx / 14, j = cpx % 14;
      int ih[2], iw[2];
      float mh[2], mw[2];
#pragma unroll
      for (int s = 0; s < 2; ++s) {
        int v = i + pa + s - 1;
        mh[s] = (v >= 0 && v <= 13) ? 1.f : 0.f;
        ih[s] = v < 0 ? 0 : (v > 13 ? 13 : v);
        int u = j + pb + s - 1;
        mw[s] = (u >= 0 && u <= 13) ? 1.f : 0.f;
        iw[s] = u < 0 ? 0 : (u > 13 ? 13 : u);
      }
      const float m00 = mh[0] * mw[0], m01 = mh[0] * mw[1];
      const float m10 = mh[1] * mw[0], m11 = mh[1] * mw[1];
      float acc[8];
#pragma unroll
      for (int oo = 0; oo < 8; ++oo) acc[oo] = b3[oo];
#pragma unroll 2
      for (int c = 0; c < 16; ++c) {
        const float a00 = d2[c * 197 + ih[0] * 14 + iw[0]] * m00;
        const float a01 = d2[c * 197 + ih[0] * 14 + iw[1]] * m01;
        const float a10 = d2[c * 197 + ih[1] * 14 + iw[0]] * m10;
        const float a11 = d2[c * 197 + ih[1] * 14 + iw[1]] * m11;
        const int wb = c * 8;
#pragma unroll
        for (int oo = 0; oo < 8; ++oo)
          acc[oo] += a00 * wA[wb + oo] + a01 * wB[wb + oo] +
                     a10 * wC[wb + oo] + a11 * wD[wb + oo];
      }
      if (px < 196) {
        const int p = 2 * i + pa, q = 2 * j + pb;
        const int widx = (p + 1) * 30 + (q + 1);
#pragma unroll
        for (int oo = 0; oo < 8; ++oo)
          d3[oo * 900 + widx] = fmaxf(acc[oo], 0.f);
      }
    }
  }
  __syncthreads();

  for (int e = t; e < 784; e += TPB) {
    int p = e / 28, q = e - p * 28;
    float a = b4[0];
#pragma unroll
    for (int c = 0; c < 8; ++c) {
      const float* bp = &d3[c * 900 + p * 30 + q];
#pragma unroll
      for (int di = 0; di < 3; ++di)
#pragma unroll
        for (int dj = 0; dj < 3; ++dj)
          a += bp[di * 30 + dj] * w4[c * 9 + di * 3 + dj];
    }
    out[(size_t)b * 784 + e] = a;
  }
}

// ---------------------------------------------------------------------------
extern "C" void kernel_launch(void* const* d_in, const int* in_sizes, int n_in,
                              void* d_out, int out_size, void* d_ws,
                              size_t ws_size, hipStream_t stream) {
  const float* x      = (const float*)d_in[0];
  const float* ce_w1  = (const float*)d_in[1];
  const float* ce_b1  = (const float*)d_in[2];
  const float* ce_w2  = (const float*)d_in[3];
  const float* ce_b2  = (const float*)d_in[4];
  const float* ce_fcw = (const float*)d_in[5];
  const float* ce_fcb = (const float*)d_in[6];
  const float* ge_w1  = (const float*)d_in[7];
  const float* ge_b1  = (const float*)d_in[8];
  const float* ge_w2  = (const float*)d_in[9];
  const float* ge_b2  = (const float*)d_in[10];
  const float* ge_fcw = (const float*)d_in[11];
  const float* ge_fcb = (const float*)d_in[12];
  const float* memg   = (const float*)d_in[13];
  const float* dfcw   = (const float*)d_in[14];
  const float* dfcb   = (const float*)d_in[15];
  const float* d_w1   = (const float*)d_in[16];
  const float* d_b1   = (const float*)d_in[17];
  const float* d_w2   = (const float*)d_in[18];
  const float* d_b2   = (const float*)d_in[19];
  const float* d_w3   = (const float*)d_in[20];
  const float* d_b3   = (const float*)d_in[21];
  const float* d_w4   = (const float*)d_in[22];
  const float* d_b4   = (const float*)d_in[23];
  float* outp = (float*)d_out;

  // ws layout (float offsets): z[262144] | zmf16[131072] | invn[8192] |
  // enc frags[36864] | dec1frags[16384] | dfcfrags[200704] |
  // memfrags[1048576] | tail (topv[327680]+topi[327680] then d0f16 — seq.)
  float*     ws        = (float*)d_ws;
  float*     z         = ws;
  _Float16*  zmf16     = (_Float16*)(ws + 262144);
  float*     invn      = ws + 262144 + 131072;
  float*     frags     = invn + 8192;
  float*     dec1frags = frags + 36864;
  float*     dfcfrags  = dec1frags + 16384;
  float*     memfrags  = dfcfrags + 200704;
  float*     tailbase  = memfrags + 1048576;
  float*     topvw     = tailbase;
  int*       topiw     = (int*)(tailbase + 327680);
  _Float16*  d0f16     = (_Float16*)tailbase;

  prep_bfrags<<<144, 64, 0, stream>>>(ce_w2, ge_w2, frags);
  prep_dec1<<<64, 64, 0, stream>>>(d_w1, dec1frags);
  prep_dfc<<<784, 64, 0, stream>>>(dfcw, dfcfrags);
  prep_mem<<<4096, 64, 0, stream>>>(memg, memfrags);
  norm_kernel<<<2048, TPB, 0, stream>>>(memg, invn);
  encoders_fused<<<4096, TPB, 0, stream>>>(x, ce_w1, ce_b1, ce_b2, ce_fcw,
                                           ce_fcb, ge_w1, ge_b1, ge_b2, ge_fcw,
                                           ge_fcb, frags, z);
  match_mfma<<<dim3(64, 16), TPB, 0, stream>>>(z, memfrags, invn, topvw, topiw);
  match_merge<<<256, TPB, 0, stream>>>(topvw, topiw, memg, zmf16);
  decfc_kernel<<<dim3(64, 2), TPB, 0, stream>>>(zmf16, dfcb, dfcfrags, d0f16);
  decoder_kernel<<<2048, TPB, 0, stream>>>(d0f16, d_b1, d_w2, d_b2, d_w3, d_b3,
                                           d_w4, d_b4, dec1frags, outp);
}